// Round 16
// baseline (1188.638 us; speedup 1.0000x reference)
//
#include <hip/hip_runtime.h>
#include <math.h>

typedef unsigned short ushort_t;
typedef __attribute__((ext_vector_type(8))) short bf16x8;
typedef __attribute__((ext_vector_type(4))) float f32x4;

// ---------- helpers ----------
__device__ inline float bf2f(unsigned u) { return __uint_as_float((u & 0xffffu) << 16); }
__device__ inline ushort_t f2bf(float f) {
    unsigned u = __float_as_uint(f);
    return (ushort_t)((u + 0x7fffu + ((u >> 16) & 1u)) >> 16);   // RNE
}
__device__ inline unsigned pack2(float a, float b) {
    return (unsigned)f2bf(a) | ((unsigned)f2bf(b) << 16);
}
__device__ inline void stv(float* p, float v) { *p = v; }
__device__ inline void stv(ushort_t* p, float v) { *p = f2bf(v); }
__device__ inline int guard_int(int raw, int lo, int hi) {
    if (raw >= lo && raw <= hi) return raw;
    float f = __int_as_float(raw);
    int v = (int)f;
    return (v >= lo && v <= hi) ? v : lo;
}

// ---------- threefry2x32 (JAX partitionable, verified R7) ----------
__device__ inline void tf2x32(unsigned k0, unsigned k1, unsigned x0, unsigned x1,
                              unsigned& o0, unsigned& o1) {
    unsigned ks2 = k0 ^ k1 ^ 0x1BD11BDAu;
    x0 += k0; x1 += k1;
#define TFR(r) { x0 += x1; x1 = (x1 << (r)) | (x1 >> (32 - (r))); x1 ^= x0; }
    TFR(13) TFR(15) TFR(26) TFR(6)  x0 += k1;  x1 += ks2 + 1u;
    TFR(17) TFR(29) TFR(16) TFR(24) x0 += ks2; x1 += k0 + 2u;
    TFR(13) TFR(15) TFR(26) TFR(6)  x0 += k0;  x1 += k1 + 3u;
    TFR(17) TFR(29) TFR(16) TFR(24) x0 += k1;  x1 += ks2 + 4u;
    TFR(13) TFR(15) TFR(26) TFR(6)  x0 += ks2; x1 += k0 + 5u;
#undef TFR
    o0 = x0; o1 = x1;
}

__global__ void k_sentinel(float* __restrict__ out, float val, int n) {
    int i = blockIdx.x * 128 + threadIdx.x;
    if (i < n) out[i] = val;
}

// ---------- diffusion categorical sampling -> one-hot X ----------
__global__ __launch_bounds__(256) void k_sample(const float* __restrict__ x,
                                                const int* __restrict__ t_ptr,
                                                float* __restrict__ X) {
    int i = blockIdx.x * 256 + threadIdx.x;
    if (i >= 4096) return;
    int tval = guard_int(t_ptr[0], 0, 500);
    double tf = (double)tval / 500.0;
    const double sc = 0.008;
    const double PI_HALF = 1.5707963267948966;
    double num = cos((tf + sc) / (1.0 + sc) * PI_HALF);
    double den = cos(sc / (1.0 + sc) * PI_HALF);
    float ab = (float)((num * num) / (den * den));
    float phi = (1.0f - ab) / 20.0f;
    float xv[20]; float sx = 0.f;
    for (int j = 0; j < 20; ++j) { xv[j] = x[i * 20 + j]; sx += xv[j]; }
    float best = -1e30f; int bj = 0;
    for (int j = 0; j < 20; ++j) {
        float prob = fmaxf(ab * xv[j] + phi * sx, 0.0f);
        float lp = logf(prob + 1e-9f);
        unsigned m = (unsigned)(i * 20 + j);
        unsigned o0, o1;
        tf2x32(0u, 42u, 0u, m, o0, o1);
        unsigned bits = o0 ^ o1;
        float u = __uint_as_float((bits >> 9) | 0x3f800000u) - 1.0f;
        if (u < 1.1754943508222875e-38f) u = 1.1754943508222875e-38f;
        float gmb = -logf(-logf(u));
        float z = lp + gmb;
        if (z > best) { best = z; bj = j; }
    }
    for (int j = 0; j < 20; ++j) X[i * 20 + j] = (j == bj) ? 1.0f : 0.0f;
}

// ---------- small utility kernels ----------
__global__ __launch_bounds__(256) void k_gather_fp(const float* __restrict__ emb,
                                                   const int* __restrict__ idx,
                                                   float* __restrict__ out) {
    int i = blockIdx.x * 256 + threadIdx.x;
    if (i >= 256 * 20) return;
    int a = i / 20, d = i % 20;
    out[i] = emb[(size_t)idx[a] * 20 + d];
}

__global__ __launch_bounds__(256) void k_scatter_bits(const int* __restrict__ ei,
                                                      unsigned* __restrict__ bits) {
    int e = blockIdx.x * 256 + threadIdx.x;
    if (e >= 65536) return;
    int r = ei[e], c = ei[65536 + e];
    atomicOr(&bits[(size_t)r * 128 + (c >> 5)], 1u << (c & 31));
}

__global__ __launch_bounds__(256) void k_degree(const unsigned* __restrict__ BITS,
                                                float* __restrict__ deg) {
    int i = blockIdx.x * 256 + threadIdx.x;
    if (i >= 4096 * 128) return;
    unsigned bits = BITS[i];
    int base = (i & 127) * 32;
    while (bits) { int b = __ffs(bits) - 1; bits &= bits - 1; atomicAdd(&deg[base + b], 1.0f); }
}

__global__ __launch_bounds__(256) void k_embed(const float* __restrict__ embw,
                                               const int* __restrict__ words,
                                               float* __restrict__ H,
                                               ushort_t* __restrict__ Hb) {
    int idx = blockIdx.x * 256 + threadIdx.x;
    if (idx >= 4096 * 512) return;
    int pos = idx >> 9, d = idx & 511;
    float e = embw[(size_t)words[pos] * 512 + d];
    float expo = (float)(d >> 1) * (1.0f / 256.0f);
    float ang = (float)pos * exp2f(-expo * 13.287712379549449f);
    float pe = (d & 1) ? cosf(ang) : sinf(ang);
    float v = e + pe;
    H[idx] = v; Hb[idx] = f2bf(v);
}

__global__ __launch_bounds__(256) void k_colmean(const float* __restrict__ M, int R, int C,
                                                 float* __restrict__ out) {
    __shared__ float red[256];
    int c = blockIdx.x, t = threadIdx.x;
    float s = 0.f;
    for (int r = t; r < R; r += 256) s += M[(size_t)r * C + c];
    red[t] = s; __syncthreads();
    for (int o = 128; o; o >>= 1) { if (t < o) red[t] += red[t + o]; __syncthreads(); }
    if (t == 0) out[c] = red[0] / (float)R;
}

__global__ __launch_bounds__(256) void k_wcolsum(const float* __restrict__ M, int R, int C,
                                                 const float* __restrict__ w,
                                                 float* __restrict__ out) {
    __shared__ float red[256];
    int c = blockIdx.x, t = threadIdx.x;
    float s = 0.f;
    for (int r = t; r < R; r += 256) s += w[r] * M[(size_t)r * C + c];
    red[t] = s; __syncthreads();
    for (int o = 128; o; o >>= 1) { if (t < o) red[t] += red[t + o]; __syncthreads(); }
    if (t == 0) out[c] = red[0];
}

// parallel matvec: block c -> out[c] = scale*(vec . W[:,c]) + bias[c]
__global__ __launch_bounds__(256) void k_matvec20(int D, float scale,
                                                  const float* __restrict__ vec,
                                                  const float* __restrict__ W,
                                                  const float* __restrict__ bias,
                                                  float* __restrict__ out) {
    __shared__ float red[256];
    int c = blockIdx.x, t = threadIdx.x;
    float s = 0.f;
    for (int d = t; d < D; d += 256) s += vec[d] * W[(size_t)d * 20 + c];
    red[t] = s; __syncthreads();
    for (int o = 128; o; o >>= 1) { if (t < o) red[t] += red[t + o]; __syncthreads(); }
    if (t == 0) out[c] = red[0] * scale + bias[c];
}

__global__ void k_gather3(const float* __restrict__ a, const float* __restrict__ b,
                          const float* __restrict__ c, float* __restrict__ out) {
    int i = blockIdx.x * 256 + threadIdx.x;
    if (i >= 1536) return;
    out[i] = (i < 512) ? a[i] : (i < 1024) ? b[i - 512] : c[i - 1024];
}

// ---------- weight cast+transpose: fp32 [K,N] -> bf16 [N,K] ----------
__global__ __launch_bounds__(256) void k_castT(const float* __restrict__ in,
                                               ushort_t* __restrict__ out,
                                               int Kd, int Nd) {
    __shared__ float t[32][33];
    int bx = blockIdx.x * 32, by = blockIdx.y * 32;
    int tx = threadIdx.x & 31, ty = threadIdx.x >> 5;
#pragma unroll
    for (int i = 0; i < 4; ++i)
        t[ty + i * 8][tx] = in[(size_t)(by + ty + i * 8) * Nd + bx + tx];
    __syncthreads();
#pragma unroll
    for (int i = 0; i < 4; ++i)
        out[(size_t)(bx + ty + i * 8) * Kd + by + tx] = f2bf(t[tx][ty + i * 8]);
}

// batched: 4x [512,512] fp32 -> bf16 transposed
__global__ __launch_bounds__(256) void k_castT4(const float* __restrict__ in0,
                                                const float* __restrict__ in1,
                                                const float* __restrict__ in2,
                                                const float* __restrict__ in3,
                                                ushort_t* __restrict__ out) {
    __shared__ float t[32][33];
    int z = blockIdx.z;
    const float* in = (z == 0) ? in0 : (z == 1) ? in1 : (z == 2) ? in2 : in3;
    ushort_t* o = out + (size_t)z * 262144;
    int bx = blockIdx.x * 32, by = blockIdx.y * 32;
    int tx = threadIdx.x & 31, ty = threadIdx.x >> 5;
#pragma unroll
    for (int i = 0; i < 4; ++i)
        t[ty + i * 8][tx] = in[(size_t)(by + ty + i * 8) * 512 + bx + tx];
    __syncthreads();
#pragma unroll
    for (int i = 0; i < 4; ++i)
        o[(size_t)(bx + ty + i * 8) * 512 + by + tx] = f2bf(t[tx][ty + i * 8]);
}

// ---------- MFMA bf16 GEMM: BM=128 x BN tile; VTR: cols>=1024 write transposed VTg ----------
template<int BN, bool RELU, bool VTR, typename TC>
__global__ __launch_bounds__(256) void k_gemm_mfma2(int M, int N, int K, int lda,
        const ushort_t* __restrict__ A,
        const ushort_t* __restrict__ Bt,
        TC* __restrict__ C, int ldc,
        const float* __restrict__ bias,
        ushort_t* __restrict__ VT) {
    constexpr int NJ = BN / 32;
    __shared__ ushort_t As[128][40];
    __shared__ ushort_t Bs[BN][40];
    int tid = threadIdx.x;
    int lane = tid & 63, wave = tid >> 6;
    int wr = wave >> 1, wc = wave & 1;
    int lrow = lane & 15, lq = lane >> 4;
    int br = blockIdx.y * 128, bc = blockIdx.x * BN;
    f32x4 acc[4][NJ];
#pragma unroll
    for (int i = 0; i < 4; ++i)
#pragma unroll
        for (int j = 0; j < NJ; ++j) { acc[i][j][0] = 0.f; acc[i][j][1] = 0.f; acc[i][j][2] = 0.f; acc[i][j][3] = 0.f; }
    int sr = tid >> 2, sseg = tid & 3;
    for (int k0 = 0; k0 < K; k0 += 32) {
#pragma unroll
        for (int it = 0; it < 2; ++it)
            *(uint4*)&As[sr + it * 64][sseg * 8] = *(const uint4*)&A[(size_t)(br + sr + it * 64) * lda + k0 + sseg * 8];
#pragma unroll
        for (int it = 0; it < BN / 64; ++it)
            *(uint4*)&Bs[sr + it * 64][sseg * 8] = *(const uint4*)&Bt[(size_t)(bc + sr + it * 64) * K + k0 + sseg * 8];
        __syncthreads();
        bf16x8 af[4], bfr[NJ];
#pragma unroll
        for (int i = 0; i < 4; ++i) af[i] = *(const bf16x8*)&As[wr * 64 + i * 16 + lrow][lq * 8];
#pragma unroll
        for (int j = 0; j < NJ; ++j) bfr[j] = *(const bf16x8*)&Bs[wc * (BN / 2) + j * 16 + lrow][lq * 8];
#pragma unroll
        for (int i = 0; i < 4; ++i)
#pragma unroll
            for (int j = 0; j < NJ; ++j)
                acc[i][j] = __builtin_amdgcn_mfma_f32_16x16x32_bf16(af[i], bfr[j], acc[i][j], 0, 0, 0);
        __syncthreads();
    }
#pragma unroll
    for (int i = 0; i < 4; ++i)
#pragma unroll
        for (int j = 0; j < NJ; ++j) {
            int col = bc + wc * (BN / 2) + j * 16 + lrow;
            float bv = bias ? bias[col] : 0.f;
            int row0 = br + wr * 64 + i * 16 + lq * 4;
            if (VTR && col >= 1024) {       // V tile: write transposed, packed 8B
                uint2 w;
                w.x = pack2(acc[i][j][0] + bv, acc[i][j][1] + bv);
                w.y = pack2(acc[i][j][2] + bv, acc[i][j][3] + bv);
                *(uint2*)&VT[(size_t)(col - 1024) * 4096 + row0] = w;
            } else {
#pragma unroll
                for (int r = 0; r < 4; ++r) {
                    float v = acc[i][j][r] + bv;
                    if (RELU) v = fmaxf(v, 0.f);
                    stv(&C[(size_t)(row0 + r) * ldc + col], v);
                }
            }
        }
}

// ---------- fp32 GEMM, 16-row x 64-col tile (tall-skinny shapes, high grid) ----------
template<bool RELU>
__global__ __launch_bounds__(256) void k_gemm_nn16(int M, int N, int K,
        const float* __restrict__ A, int lda,
        const float* __restrict__ B, int ldb,
        float* __restrict__ C, int ldc,
        const float* __restrict__ bias) {
    int tx = threadIdx.x & 63, ty = threadIdx.x >> 6;     // col, row-quad
    int br = blockIdx.y * 16, bc = blockIdx.x * 64;
    int col = bc + tx;
    bool cok = col < N;
    float acc[4] = {0.f, 0.f, 0.f, 0.f};
    for (int k = 0; k < K; ++k) {
        float b = cok ? B[(size_t)k * ldb + col] : 0.f;
#pragma unroll
        for (int i = 0; i < 4; ++i) {
            int row = br + ty * 4 + i;
            if (row < M) acc[i] += A[(size_t)row * lda + k] * b;
        }
    }
    if (!cok) return;
    float bv = bias ? bias[col] : 0.f;
#pragma unroll
    for (int i = 0; i < 4; ++i) {
        int row = br + ty * 4 + i;
        if (row < M) {
            float v = acc[i] + bv;
            if (RELU) v = fmaxf(v, 0.f);
            C[(size_t)row * ldc + col] = v;
        }
    }
}

// ---------- SpMM wave-per-(row,chunk) ----------
template<int NC, int CH>
__global__ __launch_bounds__(256) void k_spmm_wave(
        const unsigned* __restrict__ BITS,
        const float* __restrict__ B, int ldb,
        float* __restrict__ C, int ldc) {
    int gw = blockIdx.x * 4 + (threadIdx.x >> 6);
    int lane = threadIdx.x & 63;
    int row = gw / CH, cb = (gw % CH) * NC;
    if (row >= 4096) return;
    float acc[NC];
#pragma unroll
    for (int j = 0; j < NC; ++j) acc[j] = 0.f;
    const unsigned* bw = &BITS[(size_t)row * 128];
#pragma unroll
    for (int i = 0; i < 2; ++i) {
        int wd = lane * 2 + i;
        unsigned bits = bw[wd];
        int base = wd * 32;
        while (bits) {
            int b = __ffs(bits) - 1; bits &= bits - 1;
            const float* br = &B[(size_t)(base + b) * ldb + cb];
#pragma unroll
            for (int j = 0; j < NC; ++j) acc[j] += br[j];
        }
    }
#pragma unroll
    for (int j = 0; j < NC; ++j) {
#pragma unroll
        for (int off = 1; off < 64; off <<= 1) acc[j] += __shfl_xor(acc[j], off, 64);
    }
    if (lane == 0)
#pragma unroll
        for (int j = 0; j < NC; ++j) C[(size_t)row * ldc + cb + j] = acc[j];
}

// ---------- MFMA flash: split-K z=3, rescale-skip, packed Ps writes ----------
__global__ __launch_bounds__(256) void k_flash(const ushort_t* __restrict__ Qg, int ldq,
                                               const ushort_t* __restrict__ Kg, int ldk,
                                               const ushort_t* __restrict__ VTg,
                                               ushort_t* __restrict__ OP0,
                                               ushort_t* __restrict__ OP12,
                                               float* __restrict__ Mp,
                                               float* __restrict__ Lp) {
    __shared__ ushort_t Ks[32][136];
    __shared__ ushort_t Vt[128][40];
    __shared__ ushort_t Ps[4][16][40];
    __shared__ float    as_[4][16];
    __shared__ float    ls_[4][16];
    const int tid = threadIdx.x;
    const int lane = tid & 63, wid = tid >> 6;
    const int lrow = lane & 15, lq = lane >> 4;
    const int qb = blockIdx.x * 64, hh = blockIdx.y, z = blockIdx.z;
    const int kt0 = z * 43, kt1 = (z == 2) ? 128 : kt0 + 43;
    const float scale = 0.08838834764831845f;   // 1/sqrt(128)
    bf16x8 qf[4];
    {
        const ushort_t* qrow = &Qg[(size_t)(qb + wid * 16 + lrow) * ldq + hh * 128 + lq * 8];
#pragma unroll
        for (int s = 0; s < 4; ++s) qf[s] = *(const bf16x8*)&qrow[s * 32];
    }
    f32x4 o[8];
#pragma unroll
    for (int ct = 0; ct < 8; ++ct) { o[ct][0] = 0.f; o[ct][1] = 0.f; o[ct][2] = 0.f; o[ct][3] = 0.f; }
    float m = -INFINITY, l = 0.f;
    for (int kt = kt0; kt < kt1; ++kt) {
#pragma unroll
        for (int i = 0; i < 2; ++i) {
            int sid = tid + i * 256;
            int r = sid >> 4, sg = sid & 15;
            *(uint4*)&Ks[r][sg * 8] = *(const uint4*)&Kg[(size_t)(kt * 32 + r) * ldk + hh * 128 + sg * 8];
            int d = sid >> 2, c8 = sid & 3;
            *(uint4*)&Vt[d][c8 * 8] = *(const uint4*)&VTg[(size_t)(hh * 128 + d) * 4096 + kt * 32 + c8 * 8];
        }
        __syncthreads();
        f32x4 sa[2];
#pragma unroll
        for (int c = 0; c < 2; ++c) { sa[c][0] = 0.f; sa[c][1] = 0.f; sa[c][2] = 0.f; sa[c][3] = 0.f; }
#pragma unroll
        for (int c = 0; c < 2; ++c)
#pragma unroll
            for (int st = 0; st < 4; ++st) {
                bf16x8 kf = *(const bf16x8*)&Ks[c * 16 + lrow][st * 32 + lq * 8];
                sa[c] = __builtin_amdgcn_mfma_f32_16x16x32_bf16(kf, qf[st], sa[c], 0, 0, 0);
            }
        float s[8];
        float tm = -INFINITY;
#pragma unroll
        for (int c = 0; c < 2; ++c)
#pragma unroll
            for (int r = 0; r < 4; ++r) { float v = sa[c][r] * scale; s[c * 4 + r] = v; tm = fmaxf(tm, v); }
        tm = fmaxf(tm, __shfl_xor(tm, 16));
        tm = fmaxf(tm, __shfl_xor(tm, 32));
        bool up = tm > m;
        float mn = up ? tm : m;
        float a = up ? __expf(m - mn) : 1.0f;
        float su = 0.f;
        float p[8];
#pragma unroll
        for (int i = 0; i < 8; ++i) { p[i] = __expf(s[i] - mn); su += p[i]; }
        su += __shfl_xor(su, 16);
        su += __shfl_xor(su, 32);
        m = mn; l = l * a + su;
#pragma unroll
        for (int c = 0; c < 2; ++c) {       // packed 8B Ps writes
            uint2 w;
            w.x = pack2(p[c * 4 + 0], p[c * 4 + 1]);
            w.y = pack2(p[c * 4 + 2], p[c * 4 + 3]);
            *(uint2*)&Ps[wid][lrow][c * 16 + lq * 4] = w;
        }
        if (__any(up)) {
            if (lq == 0) as_[wid][lrow] = a;
            __builtin_amdgcn_s_waitcnt(0);
            float av[4];
#pragma unroll
            for (int r = 0; r < 4; ++r) av[r] = as_[wid][lq * 4 + r];
#pragma unroll
            for (int ct = 0; ct < 8; ++ct)
#pragma unroll
                for (int r = 0; r < 4; ++r) o[ct][r] *= av[r];
        } else {
            __builtin_amdgcn_s_waitcnt(0);
        }
        bf16x8 pf = *(const bf16x8*)&Ps[wid][lrow][lq * 8];
#pragma unroll
        for (int ct = 0; ct < 8; ++ct) {
            bf16x8 vf = *(const bf16x8*)&Vt[ct * 16 + lrow][lq * 8];
            o[ct] = __builtin_amdgcn_mfma_f32_16x16x32_bf16(pf, vf, o[ct], 0, 0, 0);
        }
        __syncthreads();
    }
    if (lq == 0) {
        Mp[(size_t)(z * 4 + hh) * 4096 + qb + wid * 16 + lrow] = m;
        Lp[(size_t)(z * 4 + hh) * 4096 + qb + wid * 16 + lrow] = l;
    }
    ushort_t* ob = (z == 0) ? OP0 : OP12 + (size_t)(z - 1) * 2097152;
#pragma unroll
    for (int ct = 0; ct < 8; ++ct)
#pragma unroll
        for (int r = 0; r < 4; ++r)
            ob[(size_t)(qb + wid * 16 + lq * 4 + r) * 512 + hh * 128 + ct * 16 + lrow] = f2bf(o[ct][r]);
}

// ---------- flash split-K combine (3 partials), in-place over OP0 ----------
__global__ __launch_bounds__(256) void k_fcomb(ushort_t* __restrict__ OP0,
                                               const ushort_t* __restrict__ OP12,
                                               const float* __restrict__ Mp,
                                               const float* __restrict__ Lp) {
    int idx = blockIdx.x * 256 + threadIdx.x;
    if (idx >= 4096 * 512) return;
    int row = idx >> 9, col = idx & 511;
    int hh = col >> 7;
    float m0 = Mp[hh * 4096 + row], m1 = Mp[(4 + hh) * 4096 + row], m2 = Mp[(8 + hh) * 4096 + row];
    float l0 = Lp[hh * 4096 + row], l1 = Lp[(4 + hh) * 4096 + row], l2 = Lp[(8 + hh) * 4096 + row];
    float mm = fmaxf(m0, fmaxf(m1, m2));
    float w0 = __expf(m0 - mm), w1 = __expf(m1 - mm), w2 = __expf(m2 - mm);
    float denom = l0 * w0 + l1 * w1 + l2 * w2;
    float o0 = bf2f(OP0[idx]), o1 = bf2f(OP12[idx]), o2 = bf2f(OP12[2097152 + idx]);
    OP0[idx] = f2bf((o0 * w0 + o1 * w1 + o2 * w2) / denom);
}

// ---------- residual add + layernorm ----------
__global__ __launch_bounds__(256) void k_add_ln(const float* __restrict__ A,
                                                const float* __restrict__ B,
                                                float* __restrict__ O,
                                                ushort_t* __restrict__ Ob,
                                                const float* __restrict__ g,
                                                const float* __restrict__ b) {
    __shared__ float xr[512];
    __shared__ float red[256];
    int row = blockIdx.x, t = threadIdx.x;
    const float* a = A + (size_t)row * 512;
    const float* bb = B + (size_t)row * 512;
    float ls = 0.f;
    for (int j = t; j < 512; j += 256) { float v = a[j] + bb[j]; xr[j] = v; ls += v; }
    red[t] = ls; __syncthreads();
    for (int o = 128; o; o >>= 1) { if (t < o) red[t] += red[t + o]; __syncthreads(); }
    float mean = red[0] / 512.0f; __syncthreads();
    float lv = 0.f;
    for (int j = t; j < 512; j += 256) { float d = xr[j] - mean; lv += d * d; }
    red[t] = lv; __syncthreads();
    for (int o = 128; o; o >>= 1) { if (t < o) red[t] += red[t + o]; __syncthreads(); }
    float inv = 1.0f / sqrtf(red[0] / 512.0f + 1e-5f);
    float* o_ = O + (size_t)row * 512;
    ushort_t* ob = Ob + (size_t)row * 512;
    for (int j = t; j < 512; j += 256) {
        float v = (xr[j] - mean) * inv * g[j] + b[j];
        o_[j] = v; ob[j] = f2bf(v);
    }
}

// ---------- fusion head ----------
__global__ __launch_bounds__(128) void k_fusion(const float* __restrict__ subv,
                                                const float* __restrict__ protv,
                                                const float* __restrict__ seqv,
                                                const float* __restrict__ Wtime,
                                                const float* __restrict__ btime,
                                                const float* __restrict__ Wout,
                                                const float* __restrict__ bout,
                                                const int* __restrict__ t_ptr,
                                                const int* __restrict__ lo_ptr,
                                                float* __restrict__ out) {
    __shared__ float cat[80];
    int t = threadIdx.x;
    int tval = guard_int(t_ptr[0], 0, 500);
    int L    = guard_int(lo_ptr[0], 0, 3);
    float tf = (float)((double)tval / 500.0);
    if (t < 20) {
        cat[t] = subv[t];
        cat[20 + t] = protv[t];
        cat[40 + t] = seqv[t];
        cat[60 + t] = tf * Wtime[t] + btime[t];
    }
    __syncthreads();
    for (int j = 0; j < L; ++j) {
        float acc = 0.f;
        if (t < 80) {
            for (int i2 = 0; i2 < 80; ++i2)
                acc += fmaxf(cat[i2], 0.f) * Wout[(size_t)j * 6400 + i2 * 80 + t];
            acc += bout[j * 80 + t];
        }
        __syncthreads();
        if (t < 80) cat[t] = acc;
        __syncthreads();
    }
    if (t < 80) out[t] = fmaxf(cat[t], 0.f);
    if (t < 20) out[80 + t] = seqv[t];
}

// ---------- launch ----------
extern "C" void kernel_launch(void* const* d_in, const int* in_sizes, int n_in,
                              void* d_out, int out_size, void* d_ws, size_t ws_size,
                              hipStream_t stream) {
    static const int EXP[39] = {
        81920, 65536, 200000, 2097152, 2560, 128, 8192, 64, 1280, 20,
        524288, 1024, 524288, 1024, 524288, 1024, 524288, 1024, 1024, 1024,
        2097152, 4096, 2097152, 1024, 1024, 1024, 10240, 20, 19200, 240,
        20, 20, 256, 4096, 4096, 131072, 1, 1, 1 };
    float code = 0.f;
    if (n_in != 39) code = 900.f;
    else {
        for (int i = 0; i < 39; ++i)
            if (in_sizes[i] != EXP[i]) { code = 500.f + 4.f * (float)i; break; }
    }
    const size_t REQ = (size_t)46 * 1024 * 1024;
    if (code == 0.f && ws_size < REQ) code = (float)(ws_size >> 20);
    float* out = (float*)d_out;
    if (code != 0.f) {
        k_sentinel<<<1, 128, 0, stream>>>(out, -code, out_size);
        return;
    }

    const float* x_in   = (const float*)d_in[0];
    const float* adjs_in= (const float*)d_in[1];
    const float* embfp  = (const float*)d_in[2];
    const float* embw   = (const float*)d_in[3];
    const float* gW1 = (const float*)d_in[4];  const float* gb1 = (const float*)d_in[5];
    const float* gW2 = (const float*)d_in[6];  const float* gb2 = (const float*)d_in[7];
    const float* gW3 = (const float*)d_in[8];  const float* gb3 = (const float*)d_in[9];
    const float* Wq  = (const float*)d_in[10]; const float* bq  = (const float*)d_in[11];
    const float* Wk  = (const float*)d_in[12]; const float* bk  = (const float*)d_in[13];
    const float* Wv  = (const float*)d_in[14]; const float* bv  = (const float*)d_in[15];
    const float* Wo  = (const float*)d_in[16]; const float* bo  = (const float*)d_in[17];
    const float* ln1g= (const float*)d_in[18]; const float* ln1b= (const float*)d_in[19];
    const float* Wff1= (const float*)d_in[20]; const float* bff1= (const float*)d_in[21];
    const float* Wff2= (const float*)d_in[22]; const float* bff2= (const float*)d_in[23];
    const float* ln2g= (const float*)d_in[24]; const float* ln2b= (const float*)d_in[25];
    const float* Wproj=(const float*)d_in[26]; const float* bproj=(const float*)d_in[27];
    const float* Woutw=(const float*)d_in[28]; const float* boutw=(const float*)d_in[29];
    const float* Wtime=(const float*)d_in[30]; const float* btime=(const float*)d_in[31];
    const int* fingerprints = (const int*)d_in[32];
    const int* words        = (const int*)d_in[33];
    const int* edge_index   = (const int*)d_in[35];
    const int* t_ptr        = (const int*)d_in[36];
    const int* lo_ptr       = (const int*)d_in[37];

    // ---- workspace (46 MiB) ----
    char* wsb = (char*)d_ws;
    float*    misc = (float*)wsb;
    float*    H    = (float*)(wsb + ((size_t)2  << 20));
    ushort_t* Hb   = (ushort_t*)(wsb + ((size_t)10 << 20));
    ushort_t* QKVb = (ushort_t*)(wsb + ((size_t)14 << 20));
    ushort_t* Ob   = (ushort_t*)(wsb + ((size_t)26 << 20));   // flash partial z=0 / combined O
    ushort_t* FFHb = (ushort_t*)(wsb + ((size_t)14 << 20));
    float*    T    = (float*)(wsb + ((size_t)30 << 20));
    ushort_t* OP12 = (ushort_t*)(wsb + ((size_t)30 << 20));
    ushort_t* Wscr = (ushort_t*)(wsb + ((size_t)38 << 20));
    ushort_t* VTg  = (ushort_t*)(wsb + ((size_t)42 << 20));
    unsigned* ADJB = (unsigned*)(wsb + ((size_t)26 << 20));
    float* pt0  = (float*)(wsb + ((size_t)14 << 20));
    float* ph1  = pt0 + 81920;
    float* pt1  = ph1 + 524288;
    float* ph2  = pt1 + 524288;
    float* Xoh  = misc;
    float* fpv  = misc + 81920;
    float* st0  = misc + 87040;
    float* sh1  = misc + 92160;
    float* st1  = misc + 124928;
    float* sh2  = misc + 157696;
    float* st2  = misc + 174080;
    float* sgo  = misc + 190464;
    float* subv = misc + 277504;
    float* protv= misc + 277536;
    float* seqv = misc + 277568;
    float* hmean= misc + 280000;
    float* wsum = misc + 281000;
    float* deg  = misc + 282000;
    float* bqkv = misc + 287000;
    float* Mp   = misc + 300000;
    float* Lp   = misc + 360000;

    auto g16 = [](int M, int N) { return dim3((unsigned)((N + 63) / 64), (unsigned)((M + 15) / 16), 1); };
    auto gm64  = [](int M, int N) { return dim3((unsigned)(N / 64), (unsigned)(M / 128), 1); };
    auto gm128 = [](int M, int N) { return dim3((unsigned)(N / 128), (unsigned)(M / 128), 1); };
    auto gt = [](int Kd, int Nd) { return dim3((unsigned)(Nd / 32), (unsigned)(Kd / 32), 1); };

    // 1. diffusion sampling
    k_sample<<<16, 256, 0, stream>>>(x_in, t_ptr, Xoh);

    // 2. substrate GCN (fp32, 16-row tiles: 16-32 blocks each vs 4 before)
    k_gather_fp<<<20, 256, 0, stream>>>(embfp, fingerprints, fpv);
    k_gemm_nn16<false><<<g16(256, 20), 256, 0, stream>>>(256, 20, 256, adjs_in, 256, fpv, 20, st0, 20, nullptr);
    k_gemm_nn16<true ><<<g16(256, 128), 256, 0, stream>>>(256, 128, 20, st0, 20, gW1, 128, sh1, 128, gb1);
    k_gemm_nn16<false><<<g16(256, 128), 256, 0, stream>>>(256, 128, 256, adjs_in, 256, sh1, 128, st1, 128, nullptr);
    k_gemm_nn16<true ><<<g16(256, 64), 256, 0, stream>>>(256, 64, 128, st1, 128, gW2, 64, sh2, 64, gb2);
    k_gemm_nn16<false><<<g16(256, 64), 256, 0, stream>>>(256, 64, 256, adjs_in, 256, sh2, 64, st2, 64, nullptr);
    k_gemm_nn16<false><<<g16(256, 20), 256, 0, stream>>>(256, 20, 64, st2, 64, gW3, 20, sgo, 20, gb3);
    k_colmean<<<20, 256, 0, stream>>>(sgo, 256, 20, subv);

    // 3. transformer
    k_embed<<<8192, 256, 0, stream>>>(embw, words, H, Hb);
    for (int l = 0; l < 2; ++l) {
        k_castT4<<<dim3(16, 16, 4), 256, 0, stream>>>(Wq + (size_t)l * 262144, Wk + (size_t)l * 262144,
                                                      Wv + (size_t)l * 262144, Wo + (size_t)l * 262144, Wscr);
        k_gather3<<<6, 256, 0, stream>>>(bq + l * 512, bk + l * 512, bv + l * 512, bqkv);
        // fused QKV GEMM; V tile written directly transposed into VTg
        k_gemm_mfma2<64, false, true, ushort_t><<<gm64(4096, 1536), 256, 0, stream>>>(
            4096, 1536, 512, 512, Hb, Wscr, QKVb, 1536, bqkv, VTg);
        k_flash<<<dim3(64, 4, 3), 256, 0, stream>>>(QKVb, 1536, QKVb + 512, 1536, VTg, Ob, OP12, Mp, Lp);
        k_fcomb<<<8192, 256, 0, stream>>>(Ob, OP12, Mp, Lp);
        k_gemm_mfma2<64, false, false, float><<<gm64(4096, 512), 256, 0, stream>>>(
            4096, 512, 512, 512, Ob, Wscr + 786432, T, 512, bo + l * 512, nullptr);
        k_add_ln<<<4096, 256, 0, stream>>>(H, T, H, Hb, ln1g + l * 512, ln1b + l * 512);
        k_castT<<<gt(512, 2048), 256, 0, stream>>>(Wff1 + (size_t)l * 1048576, Wscr, 512, 2048);
        k_gemm_mfma2<128, true, false, ushort_t><<<gm128(4096, 2048), 256, 0, stream>>>(
            4096, 2048, 512, 512, Hb, Wscr, FFHb, 2048, bff1 + l * 2048, nullptr);
        k_castT<<<gt(2048, 512), 256, 0, stream>>>(Wff2 + (size_t)l * 1048576, Wscr, 2048, 512);
        k_gemm_mfma2<64, false, false, float><<<gm64(4096, 512), 256, 0, stream>>>(
            4096, 512, 2048, 2048, FFHb, Wscr, T, 512, bff2 + l * 512, nullptr);
        k_add_ln<<<4096, 256, 0, stream>>>(H, T, H, Hb, ln2g + l * 512, ln2b + l * 512);
    }

    // 4. seq = mean(H) @ Wproj + bproj
    k_colmean<<<512, 256, 0, stream>>>(H, 4096, 512, hmean);
    k_matvec20<<<20, 256, 0, stream>>>(512, 1.0f, hmean, Wproj, bproj, seqv);

    // 5. protein GCN (16-row-tile GEMMs: 256-512 blocks vs 64-128 before)
    hipMemsetAsync(ADJB, 0, (size_t)4096 * 128 * 4, stream);
    hipMemsetAsync(deg, 0, 4096 * 4, stream);
    k_scatter_bits<<<256, 256, 0, stream>>>(edge_index, ADJB);
    k_spmm_wave<20, 1><<<1024, 256, 0, stream>>>(ADJB, Xoh, 20, pt0, 20);
    k_gemm_nn16<true ><<<g16(4096, 128), 256, 0, stream>>>(4096, 128, 20, pt0, 20, gW1, 128, ph1, 128, gb1);
    k_spmm_wave<32, 4><<<4096, 256, 0, stream>>>(ADJB, ph1, 128, pt1, 128);
    k_gemm_nn16<true ><<<g16(4096, 64), 256, 0, stream>>>(4096, 64, 128, pt1, 128, gW2, 64, ph2, 64, gb2);
    k_degree<<<2048, 256, 0, stream>>>(ADJB, deg);
    k_wcolsum<<<64, 256, 0, stream>>>(ph2, 4096, 64, deg, wsum);
    k_matvec20<<<20, 256, 0, stream>>>(64, 1.0f / 4096.0f, wsum, gW3, gb3, protv);

    // 6. fusion head
    k_fusion<<<1, 128, 0, stream>>>(subv, protv, seqv, Wtime, btime, Woutw, boutw, t_ptr, lo_ptr, out);
}

// Round 17
// 863.870 us; speedup vs baseline: 1.3759x; 1.3759x over previous
//
#include <hip/hip_runtime.h>
#include <math.h>

typedef unsigned short ushort_t;
typedef __attribute__((ext_vector_type(8))) short bf16x8;
typedef __attribute__((ext_vector_type(4))) float f32x4;

// ---------- helpers ----------
__device__ inline float bf2f(unsigned u) { return __uint_as_float((u & 0xffffu) << 16); }
__device__ inline ushort_t f2bf(float f) {
    unsigned u = __float_as_uint(f);
    return (ushort_t)((u + 0x7fffu + ((u >> 16) & 1u)) >> 16);   // RNE
}
__device__ inline unsigned pack2(float a, float b) {
    return (unsigned)f2bf(a) | ((unsigned)f2bf(b) << 16);
}
__device__ inline void stv(float* p, float v) { *p = v; }
__device__ inline void stv(ushort_t* p, float v) { *p = f2bf(v); }
__device__ inline int guard_int(int raw, int lo, int hi) {
    if (raw >= lo && raw <= hi) return raw;
    float f = __int_as_float(raw);
    int v = (int)f;
    return (v >= lo && v <= hi) ? v : lo;
}

// ---------- threefry2x32 (JAX partitionable, verified R7) ----------
__device__ inline void tf2x32(unsigned k0, unsigned k1, unsigned x0, unsigned x1,
                              unsigned& o0, unsigned& o1) {
    unsigned ks2 = k0 ^ k1 ^ 0x1BD11BDAu;
    x0 += k0; x1 += k1;
#define TFR(r) { x0 += x1; x1 = (x1 << (r)) | (x1 >> (32 - (r))); x1 ^= x0; }
    TFR(13) TFR(15) TFR(26) TFR(6)  x0 += k1;  x1 += ks2 + 1u;
    TFR(17) TFR(29) TFR(16) TFR(24) x0 += ks2; x1 += k0 + 2u;
    TFR(13) TFR(15) TFR(26) TFR(6)  x0 += k0;  x1 += k1 + 3u;
    TFR(17) TFR(29) TFR(16) TFR(24) x0 += k1;  x1 += ks2 + 4u;
    TFR(13) TFR(15) TFR(26) TFR(6)  x0 += ks2; x1 += k0 + 5u;
#undef TFR
    o0 = x0; o1 = x1;
}

__global__ void k_sentinel(float* __restrict__ out, float val, int n) {
    int i = blockIdx.x * 128 + threadIdx.x;
    if (i < n) out[i] = val;
}

// ---------- diffusion categorical sampling -> one-hot X ----------
__global__ __launch_bounds__(256) void k_sample(const float* __restrict__ x,
                                                const int* __restrict__ t_ptr,
                                                float* __restrict__ X) {
    int i = blockIdx.x * 256 + threadIdx.x;
    if (i >= 4096) return;
    int tval = guard_int(t_ptr[0], 0, 500);
    double tf = (double)tval / 500.0;
    const double sc = 0.008;
    const double PI_HALF = 1.5707963267948966;
    double num = cos((tf + sc) / (1.0 + sc) * PI_HALF);
    double den = cos(sc / (1.0 + sc) * PI_HALF);
    float ab = (float)((num * num) / (den * den));
    float phi = (1.0f - ab) / 20.0f;
    float xv[20]; float sx = 0.f;
    for (int j = 0; j < 20; ++j) { xv[j] = x[i * 20 + j]; sx += xv[j]; }
    float best = -1e30f; int bj = 0;
    for (int j = 0; j < 20; ++j) {
        float prob = fmaxf(ab * xv[j] + phi * sx, 0.0f);
        float lp = logf(prob + 1e-9f);
        unsigned m = (unsigned)(i * 20 + j);
        unsigned o0, o1;
        tf2x32(0u, 42u, 0u, m, o0, o1);
        unsigned bits = o0 ^ o1;
        float u = __uint_as_float((bits >> 9) | 0x3f800000u) - 1.0f;
        if (u < 1.1754943508222875e-38f) u = 1.1754943508222875e-38f;
        float gmb = -logf(-logf(u));
        float z = lp + gmb;
        if (z > best) { best = z; bj = j; }
    }
    for (int j = 0; j < 20; ++j) X[i * 20 + j] = (j == bj) ? 1.0f : 0.0f;
}

// ---------- small utility kernels ----------
__global__ __launch_bounds__(256) void k_gather_fp(const float* __restrict__ emb,
                                                   const int* __restrict__ idx,
                                                   float* __restrict__ out) {
    int i = blockIdx.x * 256 + threadIdx.x;
    if (i >= 256 * 20) return;
    int a = i / 20, d = i % 20;
    out[i] = emb[(size_t)idx[a] * 20 + d];
}

__global__ __launch_bounds__(256) void k_scatter_bits(const int* __restrict__ ei,
                                                      unsigned* __restrict__ bits) {
    int e = blockIdx.x * 256 + threadIdx.x;
    if (e >= 65536) return;
    int r = ei[e], c = ei[65536 + e];
    atomicOr(&bits[(size_t)r * 128 + (c >> 5)], 1u << (c & 31));
}

__global__ __launch_bounds__(256) void k_degree(const unsigned* __restrict__ BITS,
                                                float* __restrict__ deg) {
    int i = blockIdx.x * 256 + threadIdx.x;
    if (i >= 4096 * 128) return;
    unsigned bits = BITS[i];
    int base = (i & 127) * 32;
    while (bits) { int b = __ffs(bits) - 1; bits &= bits - 1; atomicAdd(&deg[base + b], 1.0f); }
}

__global__ __launch_bounds__(256) void k_embed(const float* __restrict__ embw,
                                               const int* __restrict__ words,
                                               float* __restrict__ H,
                                               ushort_t* __restrict__ Hb) {
    int idx = blockIdx.x * 256 + threadIdx.x;
    if (idx >= 4096 * 512) return;
    int pos = idx >> 9, d = idx & 511;
    float e = embw[(size_t)words[pos] * 512 + d];
    float expo = (float)(d >> 1) * (1.0f / 256.0f);
    float ang = (float)pos * exp2f(-expo * 13.287712379549449f);
    float pe = (d & 1) ? cosf(ang) : sinf(ang);
    float v = e + pe;
    H[idx] = v; Hb[idx] = f2bf(v);
}

__global__ __launch_bounds__(256) void k_colmean(const float* __restrict__ M, int R, int C,
                                                 float* __restrict__ out) {
    __shared__ float red[256];
    int c = blockIdx.x, t = threadIdx.x;
    float s = 0.f;
    for (int r = t; r < R; r += 256) s += M[(size_t)r * C + c];
    red[t] = s; __syncthreads();
    for (int o = 128; o; o >>= 1) { if (t < o) red[t] += red[t + o]; __syncthreads(); }
    if (t == 0) out[c] = red[0] / (float)R;
}

__global__ __launch_bounds__(256) void k_wcolsum(const float* __restrict__ M, int R, int C,
                                                 const float* __restrict__ w,
                                                 float* __restrict__ out) {
    __shared__ float red[256];
    int c = blockIdx.x, t = threadIdx.x;
    float s = 0.f;
    for (int r = t; r < R; r += 256) s += w[r] * M[(size_t)r * C + c];
    red[t] = s; __syncthreads();
    for (int o = 128; o; o >>= 1) { if (t < o) red[t] += red[t + o]; __syncthreads(); }
    if (t == 0) out[c] = red[0];
}

// parallel matvec: block c -> out[c] = scale*(vec . W[:,c]) + bias[c]
__global__ __launch_bounds__(256) void k_matvec20(int D, float scale,
                                                  const float* __restrict__ vec,
                                                  const float* __restrict__ W,
                                                  const float* __restrict__ bias,
                                                  float* __restrict__ out) {
    __shared__ float red[256];
    int c = blockIdx.x, t = threadIdx.x;
    float s = 0.f;
    for (int d = t; d < D; d += 256) s += vec[d] * W[(size_t)d * 20 + c];
    red[t] = s; __syncthreads();
    for (int o = 128; o; o >>= 1) { if (t < o) red[t] += red[t + o]; __syncthreads(); }
    if (t == 0) out[c] = red[0] * scale + bias[c];
}

__global__ void k_gather3(const float* __restrict__ a, const float* __restrict__ b,
                          const float* __restrict__ c, float* __restrict__ out) {
    int i = blockIdx.x * 256 + threadIdx.x;
    if (i >= 1536) return;
    out[i] = (i < 512) ? a[i] : (i < 1024) ? b[i - 512] : c[i - 1024];
}

// ---------- weight cast+transpose: fp32 [K,N] -> bf16 [N,K] ----------
__global__ __launch_bounds__(256) void k_castT(const float* __restrict__ in,
                                               ushort_t* __restrict__ out,
                                               int Kd, int Nd) {
    __shared__ float t[32][33];
    int bx = blockIdx.x * 32, by = blockIdx.y * 32;
    int tx = threadIdx.x & 31, ty = threadIdx.x >> 5;
#pragma unroll
    for (int i = 0; i < 4; ++i)
        t[ty + i * 8][tx] = in[(size_t)(by + ty + i * 8) * Nd + bx + tx];
    __syncthreads();
#pragma unroll
    for (int i = 0; i < 4; ++i)
        out[(size_t)(bx + ty + i * 8) * Kd + by + tx] = f2bf(t[tx][ty + i * 8]);
}

// batched: 4x [512,512] fp32 -> bf16 transposed
__global__ __launch_bounds__(256) void k_castT4(const float* __restrict__ in0,
                                                const float* __restrict__ in1,
                                                const float* __restrict__ in2,
                                                const float* __restrict__ in3,
                                                ushort_t* __restrict__ out) {
    __shared__ float t[32][33];
    int z = blockIdx.z;
    const float* in = (z == 0) ? in0 : (z == 1) ? in1 : (z == 2) ? in2 : in3;
    ushort_t* o = out + (size_t)z * 262144;
    int bx = blockIdx.x * 32, by = blockIdx.y * 32;
    int tx = threadIdx.x & 31, ty = threadIdx.x >> 5;
#pragma unroll
    for (int i = 0; i < 4; ++i)
        t[ty + i * 8][tx] = in[(size_t)(by + ty + i * 8) * 512 + bx + tx];
    __syncthreads();
#pragma unroll
    for (int i = 0; i < 4; ++i)
        o[(size_t)(bx + ty + i * 8) * 512 + by + tx] = f2bf(t[tx][ty + i * 8]);
}

// ---------- MFMA bf16 GEMM: BM=128 x BN tile; VTR: cols>=1024 write transposed VTg ----------
template<int BN, bool RELU, bool VTR, typename TC>
__global__ __launch_bounds__(256) void k_gemm_mfma2(int M, int N, int K, int lda,
        const ushort_t* __restrict__ A,
        const ushort_t* __restrict__ Bt,
        TC* __restrict__ C, int ldc,
        const float* __restrict__ bias,
        ushort_t* __restrict__ VT) {
    constexpr int NJ = BN / 32;
    __shared__ ushort_t As[128][40];
    __shared__ ushort_t Bs[BN][40];
    int tid = threadIdx.x;
    int lane = tid & 63, wave = tid >> 6;
    int wr = wave >> 1, wc = wave & 1;
    int lrow = lane & 15, lq = lane >> 4;
    int br = blockIdx.y * 128, bc = blockIdx.x * BN;
    f32x4 acc[4][NJ];
#pragma unroll
    for (int i = 0; i < 4; ++i)
#pragma unroll
        for (int j = 0; j < NJ; ++j) { acc[i][j][0] = 0.f; acc[i][j][1] = 0.f; acc[i][j][2] = 0.f; acc[i][j][3] = 0.f; }
    int sr = tid >> 2, sseg = tid & 3;
    for (int k0 = 0; k0 < K; k0 += 32) {
#pragma unroll
        for (int it = 0; it < 2; ++it)
            *(uint4*)&As[sr + it * 64][sseg * 8] = *(const uint4*)&A[(size_t)(br + sr + it * 64) * lda + k0 + sseg * 8];
#pragma unroll
        for (int it = 0; it < BN / 64; ++it)
            *(uint4*)&Bs[sr + it * 64][sseg * 8] = *(const uint4*)&Bt[(size_t)(bc + sr + it * 64) * K + k0 + sseg * 8];
        __syncthreads();
        bf16x8 af[4], bfr[NJ];
#pragma unroll
        for (int i = 0; i < 4; ++i) af[i] = *(const bf16x8*)&As[wr * 64 + i * 16 + lrow][lq * 8];
#pragma unroll
        for (int j = 0; j < NJ; ++j) bfr[j] = *(const bf16x8*)&Bs[wc * (BN / 2) + j * 16 + lrow][lq * 8];
#pragma unroll
        for (int i = 0; i < 4; ++i)
#pragma unroll
            for (int j = 0; j < NJ; ++j)
                acc[i][j] = __builtin_amdgcn_mfma_f32_16x16x32_bf16(af[i], bfr[j], acc[i][j], 0, 0, 0);
        __syncthreads();
    }
#pragma unroll
    for (int i = 0; i < 4; ++i)
#pragma unroll
        for (int j = 0; j < NJ; ++j) {
            int col = bc + wc * (BN / 2) + j * 16 + lrow;
            float bv = bias ? bias[col] : 0.f;
            int row0 = br + wr * 64 + i * 16 + lq * 4;
            if (VTR && col >= 1024) {       // V tile: write transposed, packed 8B
                uint2 w;
                w.x = pack2(acc[i][j][0] + bv, acc[i][j][1] + bv);
                w.y = pack2(acc[i][j][2] + bv, acc[i][j][3] + bv);
                *(uint2*)&VT[(size_t)(col - 1024) * 4096 + row0] = w;
            } else {
#pragma unroll
                for (int r = 0; r < 4; ++r) {
                    float v = acc[i][j][r] + bv;
                    if (RELU) v = fmaxf(v, 0.f);
                    stv(&C[(size_t)(row0 + r) * ldc + col], v);
                }
            }
        }
}

// ---------- fp32 GEMM, LDS-tiled 64x64 (R15 version — restored after R16 regression:
// serial-K k_gemm_nn16 was latency-bound at 121 us; the LDS tile is what hides latency) ----------
template<bool RELU>
__global__ __launch_bounds__(256) void k_gemm_nn(int M, int N, int K,
        const float* __restrict__ A, int lda,
        const float* __restrict__ B, int ldb,
        float* __restrict__ C, int ldc,
        const float* __restrict__ bias) {
    __shared__ float As[16][65];
    __shared__ float Bs[16][65];
    int tid = threadIdx.x;
    int tx = tid & 15, ty = tid >> 4;
    int br = blockIdx.y * 64, bc = blockIdx.x * 64;
    float acc[4][4] = {};
    for (int k0 = 0; k0 < K; k0 += 16) {
#pragma unroll
        for (int c0 = 0; c0 < 4; ++c0) {
            int r = (tid >> 4) + c0 * 16, kk = tid & 15;
            int gr = br + r, gk = k0 + kk;
            As[kk][r] = (gr < M && gk < K) ? A[(size_t)gr * lda + gk] : 0.f;
        }
#pragma unroll
        for (int c0 = 0; c0 < 4; ++c0) {
            int col = tid & 63, kk = (tid >> 6) + c0 * 4;
            int gc = bc + col, gk = k0 + kk;
            Bs[kk][col] = (gc < N && gk < K) ? B[(size_t)gk * ldb + gc] : 0.f;
        }
        __syncthreads();
#pragma unroll
        for (int kk = 0; kk < 16; ++kk) {
            float av[4], bv[4];
#pragma unroll
            for (int i2 = 0; i2 < 4; ++i2) av[i2] = As[kk][ty + 16 * i2];
#pragma unroll
            for (int j2 = 0; j2 < 4; ++j2) bv[j2] = Bs[kk][tx + 16 * j2];
#pragma unroll
            for (int i2 = 0; i2 < 4; ++i2)
#pragma unroll
                for (int j2 = 0; j2 < 4; ++j2) acc[i2][j2] += av[i2] * bv[j2];
        }
        __syncthreads();
    }
#pragma unroll
    for (int i2 = 0; i2 < 4; ++i2)
#pragma unroll
        for (int j2 = 0; j2 < 4; ++j2) {
            int r = br + ty + 16 * i2, c = bc + tx + 16 * j2;
            if (r < M && c < N) {
                float v = acc[i2][j2];
                if (bias) v += bias[c];
                if (RELU) v = fmaxf(v, 0.f);
                C[(size_t)r * ldc + c] = v;
            }
        }
}

// ---------- SpMM wave-per-(row,chunk) ----------
template<int NC, int CH>
__global__ __launch_bounds__(256) void k_spmm_wave(
        const unsigned* __restrict__ BITS,
        const float* __restrict__ B, int ldb,
        float* __restrict__ C, int ldc) {
    int gw = blockIdx.x * 4 + (threadIdx.x >> 6);
    int lane = threadIdx.x & 63;
    int row = gw / CH, cb = (gw % CH) * NC;
    if (row >= 4096) return;
    float acc[NC];
#pragma unroll
    for (int j = 0; j < NC; ++j) acc[j] = 0.f;
    const unsigned* bw = &BITS[(size_t)row * 128];
#pragma unroll
    for (int i = 0; i < 2; ++i) {
        int wd = lane * 2 + i;
        unsigned bits = bw[wd];
        int base = wd * 32;
        while (bits) {
            int b = __ffs(bits) - 1; bits &= bits - 1;
            const float* br = &B[(size_t)(base + b) * ldb + cb];
#pragma unroll
            for (int j = 0; j < NC; ++j) acc[j] += br[j];
        }
    }
#pragma unroll
    for (int j = 0; j < NC; ++j) {
#pragma unroll
        for (int off = 1; off < 64; off <<= 1) acc[j] += __shfl_xor(acc[j], off, 64);
    }
    if (lane == 0)
#pragma unroll
        for (int j = 0; j < NC; ++j) C[(size_t)row * ldc + cb + j] = acc[j];
}

// ---------- MFMA flash: split-K z=3, rescale-skip, packed Ps writes ----------
__global__ __launch_bounds__(256) void k_flash(const ushort_t* __restrict__ Qg, int ldq,
                                               const ushort_t* __restrict__ Kg, int ldk,
                                               const ushort_t* __restrict__ VTg,
                                               ushort_t* __restrict__ OP0,
                                               ushort_t* __restrict__ OP12,
                                               float* __restrict__ Mp,
                                               float* __restrict__ Lp) {
    __shared__ ushort_t Ks[32][136];
    __shared__ ushort_t Vt[128][40];
    __shared__ ushort_t Ps[4][16][40];
    __shared__ float    as_[4][16];
    __shared__ float    ls_[4][16];
    const int tid = threadIdx.x;
    const int lane = tid & 63, wid = tid >> 6;
    const int lrow = lane & 15, lq = lane >> 4;
    const int qb = blockIdx.x * 64, hh = blockIdx.y, z = blockIdx.z;
    const int kt0 = z * 43, kt1 = (z == 2) ? 128 : kt0 + 43;
    const float scale = 0.08838834764831845f;   // 1/sqrt(128)
    bf16x8 qf[4];
    {
        const ushort_t* qrow = &Qg[(size_t)(qb + wid * 16 + lrow) * ldq + hh * 128 + lq * 8];
#pragma unroll
        for (int s = 0; s < 4; ++s) qf[s] = *(const bf16x8*)&qrow[s * 32];
    }
    f32x4 o[8];
#pragma unroll
    for (int ct = 0; ct < 8; ++ct) { o[ct][0] = 0.f; o[ct][1] = 0.f; o[ct][2] = 0.f; o[ct][3] = 0.f; }
    float m = -INFINITY, l = 0.f;
    for (int kt = kt0; kt < kt1; ++kt) {
#pragma unroll
        for (int i = 0; i < 2; ++i) {
            int sid = tid + i * 256;
            int r = sid >> 4, sg = sid & 15;
            *(uint4*)&Ks[r][sg * 8] = *(const uint4*)&Kg[(size_t)(kt * 32 + r) * ldk + hh * 128 + sg * 8];
            int d = sid >> 2, c8 = sid & 3;
            *(uint4*)&Vt[d][c8 * 8] = *(const uint4*)&VTg[(size_t)(hh * 128 + d) * 4096 + kt * 32 + c8 * 8];
        }
        __syncthreads();
        f32x4 sa[2];
#pragma unroll
        for (int c = 0; c < 2; ++c) { sa[c][0] = 0.f; sa[c][1] = 0.f; sa[c][2] = 0.f; sa[c][3] = 0.f; }
#pragma unroll
        for (int c = 0; c < 2; ++c)
#pragma unroll
            for (int st = 0; st < 4; ++st) {
                bf16x8 kf = *(const bf16x8*)&Ks[c * 16 + lrow][st * 32 + lq * 8];
                sa[c] = __builtin_amdgcn_mfma_f32_16x16x32_bf16(kf, qf[st], sa[c], 0, 0, 0);
            }
        float s[8];
        float tm = -INFINITY;
#pragma unroll
        for (int c = 0; c < 2; ++c)
#pragma unroll
            for (int r = 0; r < 4; ++r) { float v = sa[c][r] * scale; s[c * 4 + r] = v; tm = fmaxf(tm, v); }
        tm = fmaxf(tm, __shfl_xor(tm, 16));
        tm = fmaxf(tm, __shfl_xor(tm, 32));
        bool up = tm > m;
        float mn = up ? tm : m;
        float a = up ? __expf(m - mn) : 1.0f;
        float su = 0.f;
        float p[8];
#pragma unroll
        for (int i = 0; i < 8; ++i) { p[i] = __expf(s[i] - mn); su += p[i]; }
        su += __shfl_xor(su, 16);
        su += __shfl_xor(su, 32);
        m = mn; l = l * a + su;
#pragma unroll
        for (int c = 0; c < 2; ++c) {       // packed 8B Ps writes
            uint2 w;
            w.x = pack2(p[c * 4 + 0], p[c * 4 + 1]);
            w.y = pack2(p[c * 4 + 2], p[c * 4 + 3]);
            *(uint2*)&Ps[wid][lrow][c * 16 + lq * 4] = w;
        }
        if (__any(up)) {
            if (lq == 0) as_[wid][lrow] = a;
            __builtin_amdgcn_s_waitcnt(0);
            float av[4];
#pragma unroll
            for (int r = 0; r < 4; ++r) av[r] = as_[wid][lq * 4 + r];
#pragma unroll
            for (int ct = 0; ct < 8; ++ct)
#pragma unroll
                for (int r = 0; r < 4; ++r) o[ct][r] *= av[r];
        } else {
            __builtin_amdgcn_s_waitcnt(0);
        }
        bf16x8 pf = *(const bf16x8*)&Ps[wid][lrow][lq * 8];
#pragma unroll
        for (int ct = 0; ct < 8; ++ct) {
            bf16x8 vf = *(const bf16x8*)&Vt[ct * 16 + lrow][lq * 8];
            o[ct] = __builtin_amdgcn_mfma_f32_16x16x32_bf16(pf, vf, o[ct], 0, 0, 0);
        }
        __syncthreads();
    }
    if (lq == 0) {
        Mp[(size_t)(z * 4 + hh) * 4096 + qb + wid * 16 + lrow] = m;
        Lp[(size_t)(z * 4 + hh) * 4096 + qb + wid * 16 + lrow] = l;
    }
    ushort_t* ob = (z == 0) ? OP0 : OP12 + (size_t)(z - 1) * 2097152;
#pragma unroll
    for (int ct = 0; ct < 8; ++ct)
#pragma unroll
        for (int r = 0; r < 4; ++r)
            ob[(size_t)(qb + wid * 16 + lq * 4 + r) * 512 + hh * 128 + ct * 16 + lrow] = f2bf(o[ct][r]);
}

// ---------- flash split-K combine (3 partials), in-place over OP0 ----------
__global__ __launch_bounds__(256) void k_fcomb(ushort_t* __restrict__ OP0,
                                               const ushort_t* __restrict__ OP12,
                                               const float* __restrict__ Mp,
                                               const float* __restrict__ Lp) {
    int idx = blockIdx.x * 256 + threadIdx.x;
    if (idx >= 4096 * 512) return;
    int row = idx >> 9, col = idx & 511;
    int hh = col >> 7;
    float m0 = Mp[hh * 4096 + row], m1 = Mp[(4 + hh) * 4096 + row], m2 = Mp[(8 + hh) * 4096 + row];
    float l0 = Lp[hh * 4096 + row], l1 = Lp[(4 + hh) * 4096 + row], l2 = Lp[(8 + hh) * 4096 + row];
    float mm = fmaxf(m0, fmaxf(m1, m2));
    float w0 = __expf(m0 - mm), w1 = __expf(m1 - mm), w2 = __expf(m2 - mm);
    float denom = l0 * w0 + l1 * w1 + l2 * w2;
    float o0 = bf2f(OP0[idx]), o1 = bf2f(OP12[idx]), o2 = bf2f(OP12[2097152 + idx]);
    OP0[idx] = f2bf((o0 * w0 + o1 * w1 + o2 * w2) / denom);
}

// ---------- residual add + layernorm ----------
__global__ __launch_bounds__(256) void k_add_ln(const float* __restrict__ A,
                                                const float* __restrict__ B,
                                                float* __restrict__ O,
                                                ushort_t* __restrict__ Ob,
                                                const float* __restrict__ g,
                                                const float* __restrict__ b) {
    __shared__ float xr[512];
    __shared__ float red[256];
    int row = blockIdx.x, t = threadIdx.x;
    const float* a = A + (size_t)row * 512;
    const float* bb = B + (size_t)row * 512;
    float ls = 0.f;
    for (int j = t; j < 512; j += 256) { float v = a[j] + bb[j]; xr[j] = v; ls += v; }
    red[t] = ls; __syncthreads();
    for (int o = 128; o; o >>= 1) { if (t < o) red[t] += red[t + o]; __syncthreads(); }
    float mean = red[0] / 512.0f; __syncthreads();
    float lv = 0.f;
    for (int j = t; j < 512; j += 256) { float d = xr[j] - mean; lv += d * d; }
    red[t] = lv; __syncthreads();
    for (int o = 128; o; o >>= 1) { if (t < o) red[t] += red[t + o]; __syncthreads(); }
    float inv = 1.0f / sqrtf(red[0] / 512.0f + 1e-5f);
    float* o_ = O + (size_t)row * 512;
    ushort_t* ob = Ob + (size_t)row * 512;
    for (int j = t; j < 512; j += 256) {
        float v = (xr[j] - mean) * inv * g[j] + b[j];
        o_[j] = v; ob[j] = f2bf(v);
    }
}

// ---------- fusion head ----------
__global__ __launch_bounds__(128) void k_fusion(const float* __restrict__ subv,
                                                const float* __restrict__ protv,
                                                const float* __restrict__ seqv,
                                                const float* __restrict__ Wtime,
                                                const float* __restrict__ btime,
                                                const float* __restrict__ Wout,
                                                const float* __restrict__ bout,
                                                const int* __restrict__ t_ptr,
                                                const int* __restrict__ lo_ptr,
                                                float* __restrict__ out) {
    __shared__ float cat[80];
    int t = threadIdx.x;
    int tval = guard_int(t_ptr[0], 0, 500);
    int L    = guard_int(lo_ptr[0], 0, 3);
    float tf = (float)((double)tval / 500.0);
    if (t < 20) {
        cat[t] = subv[t];
        cat[20 + t] = protv[t];
        cat[40 + t] = seqv[t];
        cat[60 + t] = tf * Wtime[t] + btime[t];
    }
    __syncthreads();
    for (int j = 0; j < L; ++j) {
        float acc = 0.f;
        if (t < 80) {
            for (int i2 = 0; i2 < 80; ++i2)
                acc += fmaxf(cat[i2], 0.f) * Wout[(size_t)j * 6400 + i2 * 80 + t];
            acc += bout[j * 80 + t];
        }
        __syncthreads();
        if (t < 80) cat[t] = acc;
        __syncthreads();
    }
    if (t < 80) out[t] = fmaxf(cat[t], 0.f);
    if (t < 20) out[80 + t] = seqv[t];
}

// ---------- launch ----------
extern "C" void kernel_launch(void* const* d_in, const int* in_sizes, int n_in,
                              void* d_out, int out_size, void* d_ws, size_t ws_size,
                              hipStream_t stream) {
    static const int EXP[39] = {
        81920, 65536, 200000, 2097152, 2560, 128, 8192, 64, 1280, 20,
        524288, 1024, 524288, 1024, 524288, 1024, 524288, 1024, 1024, 1024,
        2097152, 4096, 2097152, 1024, 1024, 1024, 10240, 20, 19200, 240,
        20, 20, 256, 4096, 4096, 131072, 1, 1, 1 };
    float code = 0.f;
    if (n_in != 39) code = 900.f;
    else {
        for (int i = 0; i < 39; ++i)
            if (in_sizes[i] != EXP[i]) { code = 500.f + 4.f * (float)i; break; }
    }
    const size_t REQ = (size_t)46 * 1024 * 1024;
    if (code == 0.f && ws_size < REQ) code = (float)(ws_size >> 20);
    float* out = (float*)d_out;
    if (code != 0.f) {
        k_sentinel<<<1, 128, 0, stream>>>(out, -code, out_size);
        return;
    }

    const float* x_in   = (const float*)d_in[0];
    const float* adjs_in= (const float*)d_in[1];
    const float* embfp  = (const float*)d_in[2];
    const float* embw   = (const float*)d_in[3];
    const float* gW1 = (const float*)d_in[4];  const float* gb1 = (const float*)d_in[5];
    const float* gW2 = (const float*)d_in[6];  const float* gb2 = (const float*)d_in[7];
    const float* gW3 = (const float*)d_in[8];  const float* gb3 = (const float*)d_in[9];
    const float* Wq  = (const float*)d_in[10]; const float* bq  = (const float*)d_in[11];
    const float* Wk  = (const float*)d_in[12]; const float* bk  = (const float*)d_in[13];
    const float* Wv  = (const float*)d_in[14]; const float* bv  = (const float*)d_in[15];
    const float* Wo  = (const float*)d_in[16]; const float* bo  = (const float*)d_in[17];
    const float* ln1g= (const float*)d_in[18]; const float* ln1b= (const float*)d_in[19];
    const float* Wff1= (const float*)d_in[20]; const float* bff1= (const float*)d_in[21];
    const float* Wff2= (const float*)d_in[22]; const float* bff2= (const float*)d_in[23];
    const float* ln2g= (const float*)d_in[24]; const float* ln2b= (const float*)d_in[25];
    const float* Wproj=(const float*)d_in[26]; const float* bproj=(const float*)d_in[27];
    const float* Woutw=(const float*)d_in[28]; const float* boutw=(const float*)d_in[29];
    const float* Wtime=(const float*)d_in[30]; const float* btime=(const float*)d_in[31];
    const int* fingerprints = (const int*)d_in[32];
    const int* words        = (const int*)d_in[33];
    const int* edge_index   = (const int*)d_in[35];
    const int* t_ptr        = (const int*)d_in[36];
    const int* lo_ptr       = (const int*)d_in[37];

    // ---- workspace (46 MiB) ----
    char* wsb = (char*)d_ws;
    float*    misc = (float*)wsb;
    float*    H    = (float*)(wsb + ((size_t)2  << 20));
    ushort_t* Hb   = (ushort_t*)(wsb + ((size_t)10 << 20));
    ushort_t* QKVb = (ushort_t*)(wsb + ((size_t)14 << 20));
    ushort_t* Ob   = (ushort_t*)(wsb + ((size_t)26 << 20));   // flash partial z=0 / combined O
    ushort_t* FFHb = (ushort_t*)(wsb + ((size_t)14 << 20));
    float*    T    = (float*)(wsb + ((size_t)30 << 20));
    ushort_t* OP12 = (ushort_t*)(wsb + ((size_t)30 << 20));
    ushort_t* Wscr = (ushort_t*)(wsb + ((size_t)38 << 20));
    ushort_t* VTg  = (ushort_t*)(wsb + ((size_t)42 << 20));
    unsigned* ADJB = (unsigned*)(wsb + ((size_t)26 << 20));
    float* pt0  = (float*)(wsb + ((size_t)14 << 20));
    float* ph1  = pt0 + 81920;
    float* pt1  = ph1 + 524288;
    float* ph2  = pt1 + 524288;
    float* Xoh  = misc;
    float* fpv  = misc + 81920;
    float* st0  = misc + 87040;
    float* sh1  = misc + 92160;
    float* st1  = misc + 124928;
    float* sh2  = misc + 157696;
    float* st2  = misc + 174080;
    float* sgo  = misc + 190464;
    float* subv = misc + 277504;
    float* protv= misc + 277536;
    float* seqv = misc + 277568;
    float* hmean= misc + 280000;
    float* wsum = misc + 281000;
    float* deg  = misc + 282000;
    float* bqkv = misc + 287000;
    float* Mp   = misc + 300000;
    float* Lp   = misc + 360000;

    auto g2 = [](int M, int N) { return dim3((unsigned)((N + 63) / 64), (unsigned)((M + 63) / 64), 1); };
    auto gm64  = [](int M, int N) { return dim3((unsigned)(N / 64), (unsigned)(M / 128), 1); };
    auto gm128 = [](int M, int N) { return dim3((unsigned)(N / 128), (unsigned)(M / 128), 1); };
    auto gt = [](int Kd, int Nd) { return dim3((unsigned)(Nd / 32), (unsigned)(Kd / 32), 1); };

    // 1. diffusion sampling
    k_sample<<<16, 256, 0, stream>>>(x_in, t_ptr, Xoh);

    // 2. substrate GCN (LDS-tiled fp32 GEMMs — restored)
    k_gather_fp<<<20, 256, 0, stream>>>(embfp, fingerprints, fpv);
    k_gemm_nn<false><<<g2(256, 20), 256, 0, stream>>>(256, 20, 256, adjs_in, 256, fpv, 20, st0, 20, nullptr);
    k_gemm_nn<true ><<<g2(256, 128), 256, 0, stream>>>(256, 128, 20, st0, 20, gW1, 128, sh1, 128, gb1);
    k_gemm_nn<false><<<g2(256, 128), 256, 0, stream>>>(256, 128, 256, adjs_in, 256, sh1, 128, st1, 128, nullptr);
    k_gemm_nn<true ><<<g2(256, 64), 256, 0, stream>>>(256, 64, 128, st1, 128, gW2, 64, sh2, 64, gb2);
    k_gemm_nn<false><<<g2(256, 64), 256, 0, stream>>>(256, 64, 256, adjs_in, 256, sh2, 64, st2, 64, nullptr);
    k_gemm_nn<false><<<g2(256, 20), 256, 0, stream>>>(256, 20, 64, st2, 64, gW3, 20, sgo, 20, gb3);
    k_colmean<<<20, 256, 0, stream>>>(sgo, 256, 20, subv);

    // 3. transformer
    k_embed<<<8192, 256, 0, stream>>>(embw, words, H, Hb);
    for (int l = 0; l < 2; ++l) {
        k_castT4<<<dim3(16, 16, 4), 256, 0, stream>>>(Wq + (size_t)l * 262144, Wk + (size_t)l * 262144,
                                                      Wv + (size_t)l * 262144, Wo + (size_t)l * 262144, Wscr);
        k_gather3<<<6, 256, 0, stream>>>(bq + l * 512, bk + l * 512, bv + l * 512, bqkv);
        k_gemm_mfma2<64, false, true, ushort_t><<<gm64(4096, 1536), 256, 0, stream>>>(
            4096, 1536, 512, 512, Hb, Wscr, QKVb, 1536, bqkv, VTg);
        k_flash<<<dim3(64, 4, 3), 256, 0, stream>>>(QKVb, 1536, QKVb + 512, 1536, VTg, Ob, OP12, Mp, Lp);
        k_fcomb<<<8192, 256, 0, stream>>>(Ob, OP12, Mp, Lp);
        k_gemm_mfma2<64, false, false, float><<<gm64(4096, 512), 256, 0, stream>>>(
            4096, 512, 512, 512, Ob, Wscr + 786432, T, 512, bo + l * 512, nullptr);
        k_add_ln<<<4096, 256, 0, stream>>>(H, T, H, Hb, ln1g + l * 512, ln1b + l * 512);
        k_castT<<<gt(512, 2048), 256, 0, stream>>>(Wff1 + (size_t)l * 1048576, Wscr, 512, 2048);
        k_gemm_mfma2<128, true, false, ushort_t><<<gm128(4096, 2048), 256, 0, stream>>>(
            4096, 2048, 512, 512, Hb, Wscr, FFHb, 2048, bff1 + l * 2048, nullptr);
        k_castT<<<gt(2048, 512), 256, 0, stream>>>(Wff2 + (size_t)l * 1048576, Wscr, 2048, 512);
        k_gemm_mfma2<64, false, false, float><<<gm64(4096, 512), 256, 0, stream>>>(
            4096, 512, 2048, 2048, FFHb, Wscr, T, 512, bff2 + l * 512, nullptr);
        k_add_ln<<<4096, 256, 0, stream>>>(H, T, H, Hb, ln2g + l * 512, ln2b + l * 512);
    }

    // 4. seq = mean(H) @ Wproj + bproj
    k_colmean<<<512, 256, 0, stream>>>(H, 4096, 512, hmean);
    k_matvec20<<<20, 256, 0, stream>>>(512, 1.0f, hmean, Wproj, bproj, seqv);

    // 5. protein GCN (LDS-tiled fp32 GEMMs — restored)
    hipMemsetAsync(ADJB, 0, (size_t)4096 * 128 * 4, stream);
    hipMemsetAsync(deg, 0, 4096 * 4, stream);
    k_scatter_bits<<<256, 256, 0, stream>>>(edge_index, ADJB);
    k_spmm_wave<20, 1><<<1024, 256, 0, stream>>>(ADJB, Xoh, 20, pt0, 20);
    k_gemm_nn<true ><<<g2(4096, 128), 256, 0, stream>>>(4096, 128, 20, pt0, 20, gW1, 128, ph1, 128, gb1);
    k_spmm_wave<32, 4><<<4096, 256, 0, stream>>>(ADJB, ph1, 128, pt1, 128);
    k_gemm_nn<true ><<<g2(4096, 64), 256, 0, stream>>>(4096, 64, 128, pt1, 128, gW2, 64, ph2, 64, gb2);
    k_degree<<<2048, 256, 0, stream>>>(ADJB, deg);
    k_wcolsum<<<64, 256, 0, stream>>>(ph2, 4096, 64, deg, wsum);
    k_matvec20<<<20, 256, 0, stream>>>(64, 1.0f / 4096.0f, wsum, gW3, gb3, protv);

    // 6. fusion head
    k_fusion<<<1, 128, 0, stream>>>(subv, protv, seqv, Wtime, btime, Woutw, boutw, t_ptr, lo_ptr, out);
}

// Round 18
// 855.842 us; speedup vs baseline: 1.3889x; 1.0094x over previous
//
#include <hip/hip_runtime.h>
#include <math.h>

typedef unsigned short ushort_t;
typedef __attribute__((ext_vector_type(8))) short bf16x8;
typedef __attribute__((ext_vector_type(4))) float f32x4;

// ---------- helpers ----------
__device__ inline float bf2f(unsigned u) { return __uint_as_float((u & 0xffffu) << 16); }
__device__ inline ushort_t f2bf(float f) {
    unsigned u = __float_as_uint(f);
    return (ushort_t)((u + 0x7fffu + ((u >> 16) & 1u)) >> 16);   // RNE
}
__device__ inline unsigned pack2(float a, float b) {
    return (unsigned)f2bf(a) | ((unsigned)f2bf(b) << 16);
}
__device__ inline void stv(float* p, float v) { *p = v; }
__device__ inline void stv(ushort_t* p, float v) { *p = f2bf(v); }
__device__ inline int guard_int(int raw, int lo, int hi) {
    if (raw >= lo && raw <= hi) return raw;
    float f = __int_as_float(raw);
    int v = (int)f;
    return (v >= lo && v <= hi) ? v : lo;
}

// ---------- threefry2x32 (JAX partitionable, verified R7) ----------
__device__ inline void tf2x32(unsigned k0, unsigned k1, unsigned x0, unsigned x1,
                              unsigned& o0, unsigned& o1) {
    unsigned ks2 = k0 ^ k1 ^ 0x1BD11BDAu;
    x0 += k0; x1 += k1;
#define TFR(r) { x0 += x1; x1 = (x1 << (r)) | (x1 >> (32 - (r))); x1 ^= x0; }
    TFR(13) TFR(15) TFR(26) TFR(6)  x0 += k1;  x1 += ks2 + 1u;
    TFR(17) TFR(29) TFR(16) TFR(24) x0 += ks2; x1 += k0 + 2u;
    TFR(13) TFR(15) TFR(26) TFR(6)  x0 += k0;  x1 += k1 + 3u;
    TFR(17) TFR(29) TFR(16) TFR(24) x0 += k1;  x1 += ks2 + 4u;
    TFR(13) TFR(15) TFR(26) TFR(6)  x0 += ks2; x1 += k0 + 5u;
#undef TFR
    o0 = x0; o1 = x1;
}

__global__ void k_sentinel(float* __restrict__ out, float val, int n) {
    int i = blockIdx.x * 128 + threadIdx.x;
    if (i < n) out[i] = val;
}

// ---------- diffusion categorical sampling -> one-hot X ----------
__global__ __launch_bounds__(256) void k_sample(const float* __restrict__ x,
                                                const int* __restrict__ t_ptr,
                                                float* __restrict__ X) {
    int i = blockIdx.x * 256 + threadIdx.x;
    if (i >= 4096) return;
    int tval = guard_int(t_ptr[0], 0, 500);
    double tf = (double)tval / 500.0;
    const double sc = 0.008;
    const double PI_HALF = 1.5707963267948966;
    double num = cos((tf + sc) / (1.0 + sc) * PI_HALF);
    double den = cos(sc / (1.0 + sc) * PI_HALF);
    float ab = (float)((num * num) / (den * den));
    float phi = (1.0f - ab) / 20.0f;
    float xv[20]; float sx = 0.f;
    for (int j = 0; j < 20; ++j) { xv[j] = x[i * 20 + j]; sx += xv[j]; }
    float best = -1e30f; int bj = 0;
    for (int j = 0; j < 20; ++j) {
        float prob = fmaxf(ab * xv[j] + phi * sx, 0.0f);
        float lp = logf(prob + 1e-9f);
        unsigned m = (unsigned)(i * 20 + j);
        unsigned o0, o1;
        tf2x32(0u, 42u, 0u, m, o0, o1);
        unsigned bits = o0 ^ o1;
        float u = __uint_as_float((bits >> 9) | 0x3f800000u) - 1.0f;
        if (u < 1.1754943508222875e-38f) u = 1.1754943508222875e-38f;
        float gmb = -logf(-logf(u));
        float z = lp + gmb;
        if (z > best) { best = z; bj = j; }
    }
    for (int j = 0; j < 20; ++j) X[i * 20 + j] = (j == bj) ? 1.0f : 0.0f;
}

// ---------- small utility kernels ----------
__global__ __launch_bounds__(256) void k_gather_fp(const float* __restrict__ emb,
                                                   const int* __restrict__ idx,
                                                   float* __restrict__ out) {
    int i = blockIdx.x * 256 + threadIdx.x;
    if (i >= 256 * 20) return;
    int a = i / 20, d = i % 20;
    out[i] = emb[(size_t)idx[a] * 20 + d];
}

__global__ __launch_bounds__(256) void k_scatter_bits(const int* __restrict__ ei,
                                                      unsigned* __restrict__ bits) {
    int e = blockIdx.x * 256 + threadIdx.x;
    if (e >= 65536) return;
    int r = ei[e], c = ei[65536 + e];
    atomicOr(&bits[(size_t)r * 128 + (c >> 5)], 1u << (c & 31));
}

__global__ __launch_bounds__(256) void k_degree(const unsigned* __restrict__ BITS,
                                                float* __restrict__ deg) {
    int i = blockIdx.x * 256 + threadIdx.x;
    if (i >= 4096 * 128) return;
    unsigned bits = BITS[i];
    int base = (i & 127) * 32;
    while (bits) { int b = __ffs(bits) - 1; bits &= bits - 1; atomicAdd(&deg[base + b], 1.0f); }
}

__global__ __launch_bounds__(256) void k_embed(const float* __restrict__ embw,
                                               const int* __restrict__ words,
                                               float* __restrict__ H,
                                               ushort_t* __restrict__ Hb) {
    int idx = blockIdx.x * 256 + threadIdx.x;
    if (idx >= 4096 * 512) return;
    int pos = idx >> 9, d = idx & 511;
    float e = embw[(size_t)words[pos] * 512 + d];
    float expo = (float)(d >> 1) * (1.0f / 256.0f);
    float ang = (float)pos * exp2f(-expo * 13.287712379549449f);
    float pe = (d & 1) ? cosf(ang) : sinf(ang);
    float v = e + pe;
    H[idx] = v; Hb[idx] = f2bf(v);
}

__global__ __launch_bounds__(256) void k_colmean(const float* __restrict__ M, int R, int C,
                                                 float* __restrict__ out) {
    __shared__ float red[256];
    int c = blockIdx.x, t = threadIdx.x;
    float s = 0.f;
    for (int r = t; r < R; r += 256) s += M[(size_t)r * C + c];
    red[t] = s; __syncthreads();
    for (int o = 128; o; o >>= 1) { if (t < o) red[t] += red[t + o]; __syncthreads(); }
    if (t == 0) out[c] = red[0] / (float)R;
}

__global__ __launch_bounds__(256) void k_wcolsum(const float* __restrict__ M, int R, int C,
                                                 const float* __restrict__ w,
                                                 float* __restrict__ out) {
    __shared__ float red[256];
    int c = blockIdx.x, t = threadIdx.x;
    float s = 0.f;
    for (int r = t; r < R; r += 256) s += w[r] * M[(size_t)r * C + c];
    red[t] = s; __syncthreads();
    for (int o = 128; o; o >>= 1) { if (t < o) red[t] += red[t + o]; __syncthreads(); }
    if (t == 0) out[c] = red[0];
}

__global__ __launch_bounds__(256) void k_matvec20(int D, float scale,
                                                  const float* __restrict__ vec,
                                                  const float* __restrict__ W,
                                                  const float* __restrict__ bias,
                                                  float* __restrict__ out) {
    __shared__ float red[256];
    int c = blockIdx.x, t = threadIdx.x;
    float s = 0.f;
    for (int d = t; d < D; d += 256) s += vec[d] * W[(size_t)d * 20 + c];
    red[t] = s; __syncthreads();
    for (int o = 128; o; o >>= 1) { if (t < o) red[t] += red[t + o]; __syncthreads(); }
    if (t == 0) out[c] = red[0] * scale + bias[c];
}

__global__ void k_gather3(const float* __restrict__ a, const float* __restrict__ b,
                          const float* __restrict__ c, float* __restrict__ out) {
    int i = blockIdx.x * 256 + threadIdx.x;
    if (i >= 1536) return;
    out[i] = (i < 512) ? a[i] : (i < 1024) ? b[i - 512] : c[i - 1024];
}

// ---------- weight cast+transpose: fp32 [K,N] -> bf16 [N,K] ----------
__global__ __launch_bounds__(256) void k_castT(const float* __restrict__ in,
                                               ushort_t* __restrict__ out,
                                               int Kd, int Nd) {
    __shared__ float t[32][33];
    int bx = blockIdx.x * 32, by = blockIdx.y * 32;
    int tx = threadIdx.x & 31, ty = threadIdx.x >> 5;
#pragma unroll
    for (int i = 0; i < 4; ++i)
        t[ty + i * 8][tx] = in[(size_t)(by + ty + i * 8) * Nd + bx + tx];
    __syncthreads();
#pragma unroll
    for (int i = 0; i < 4; ++i)
        out[(size_t)(bx + ty + i * 8) * Kd + by + tx] = f2bf(t[tx][ty + i * 8]);
}

// batched: 4x [512,512] fp32 -> bf16 transposed
__global__ __launch_bounds__(256) void k_castT4(const float* __restrict__ in0,
                                                const float* __restrict__ in1,
                                                const float* __restrict__ in2,
                                                const float* __restrict__ in3,
                                                ushort_t* __restrict__ out) {
    __shared__ float t[32][33];
    int z = blockIdx.z;
    const float* in = (z == 0) ? in0 : (z == 1) ? in1 : (z == 2) ? in2 : in3;
    ushort_t* o = out + (size_t)z * 262144;
    int bx = blockIdx.x * 32, by = blockIdx.y * 32;
    int tx = threadIdx.x & 31, ty = threadIdx.x >> 5;
#pragma unroll
    for (int i = 0; i < 4; ++i)
        t[ty + i * 8][tx] = in[(size_t)(by + ty + i * 8) * 512 + bx + tx];
    __syncthreads();
#pragma unroll
    for (int i = 0; i < 4; ++i)
        o[(size_t)(bx + ty + i * 8) * 512 + by + tx] = f2bf(t[tx][ty + i * 8]);
}

// ---------- MFMA bf16 GEMM: BM=128 x BN tile; VTR: cols>=1024 write transposed VTg ----------
template<int BN, bool RELU, bool VTR, typename TC>
__global__ __launch_bounds__(256) void k_gemm_mfma2(int M, int N, int K, int lda,
        const ushort_t* __restrict__ A,
        const ushort_t* __restrict__ Bt,
        TC* __restrict__ C, int ldc,
        const float* __restrict__ bias,
        ushort_t* __restrict__ VT) {
    constexpr int NJ = BN / 32;
    __shared__ ushort_t As[128][40];
    __shared__ ushort_t Bs[BN][40];
    int tid = threadIdx.x;
    int lane = tid & 63, wave = tid >> 6;
    int wr = wave >> 1, wc = wave & 1;
    int lrow = lane & 15, lq = lane >> 4;
    int br = blockIdx.y * 128, bc = blockIdx.x * BN;
    f32x4 acc[4][NJ];
#pragma unroll
    for (int i = 0; i < 4; ++i)
#pragma unroll
        for (int j = 0; j < NJ; ++j) { acc[i][j][0] = 0.f; acc[i][j][1] = 0.f; acc[i][j][2] = 0.f; acc[i][j][3] = 0.f; }
    int sr = tid >> 2, sseg = tid & 3;
    for (int k0 = 0; k0 < K; k0 += 32) {
#pragma unroll
        for (int it = 0; it < 2; ++it)
            *(uint4*)&As[sr + it * 64][sseg * 8] = *(const uint4*)&A[(size_t)(br + sr + it * 64) * lda + k0 + sseg * 8];
#pragma unroll
        for (int it = 0; it < BN / 64; ++it)
            *(uint4*)&Bs[sr + it * 64][sseg * 8] = *(const uint4*)&Bt[(size_t)(bc + sr + it * 64) * K + k0 + sseg * 8];
        __syncthreads();
        bf16x8 af[4], bfr[NJ];
#pragma unroll
        for (int i = 0; i < 4; ++i) af[i] = *(const bf16x8*)&As[wr * 64 + i * 16 + lrow][lq * 8];
#pragma unroll
        for (int j = 0; j < NJ; ++j) bfr[j] = *(const bf16x8*)&Bs[wc * (BN / 2) + j * 16 + lrow][lq * 8];
#pragma unroll
        for (int i = 0; i < 4; ++i)
#pragma unroll
            for (int j = 0; j < NJ; ++j)
                acc[i][j] = __builtin_amdgcn_mfma_f32_16x16x32_bf16(af[i], bfr[j], acc[i][j], 0, 0, 0);
        __syncthreads();
    }
#pragma unroll
    for (int i = 0; i < 4; ++i)
#pragma unroll
        for (int j = 0; j < NJ; ++j) {
            int col = bc + wc * (BN / 2) + j * 16 + lrow;
            float bv = bias ? bias[col] : 0.f;
            int row0 = br + wr * 64 + i * 16 + lq * 4;
            if (VTR && col >= 1024) {
                uint2 w;
                w.x = pack2(acc[i][j][0] + bv, acc[i][j][1] + bv);
                w.y = pack2(acc[i][j][2] + bv, acc[i][j][3] + bv);
                *(uint2*)&VT[(size_t)(col - 1024) * 4096 + row0] = w;
            } else {
#pragma unroll
                for (int r = 0; r < 4; ++r) {
                    float v = acc[i][j][r] + bv;
                    if (RELU) v = fmaxf(v, 0.f);
                    stv(&C[(size_t)(row0 + r) * ldc + col], v);
                }
            }
        }
}

// ---------- MFMA bf16 GEMM 64x64 tile (R9-proven) — for N=512 shapes: grid 512 = 2/CU
// (BM=128 gave these 256 blocks = 1/CU; R11's under-delivery traced here) ----------
template<bool RELU, typename TC>
__global__ __launch_bounds__(256) void k_gemm_mfma64(int M, int N, int K, int lda,
        const ushort_t* __restrict__ A,
        const ushort_t* __restrict__ Bt,
        TC* __restrict__ C, int ldc,
        const float* __restrict__ bias) {
    __shared__ ushort_t As[64][40];
    __shared__ ushort_t Bs[64][40];
    int tid = threadIdx.x;
    int lane = tid & 63, wave = tid >> 6;
    int wr = wave >> 1, wc = wave & 1;
    int lrow = lane & 15, lq = lane >> 4;
    int br = blockIdx.y * 64, bc = blockIdx.x * 64;
    f32x4 acc[2][2];
#pragma unroll
    for (int i = 0; i < 2; ++i)
#pragma unroll
        for (int j = 0; j < 2; ++j) { acc[i][j][0] = 0.f; acc[i][j][1] = 0.f; acc[i][j][2] = 0.f; acc[i][j][3] = 0.f; }
    int sr = tid >> 2, sseg = tid & 3;
    for (int k0 = 0; k0 < K; k0 += 32) {
        *(uint4*)&As[sr][sseg * 8] = *(const uint4*)&A[(size_t)(br + sr) * lda + k0 + sseg * 8];
        *(uint4*)&Bs[sr][sseg * 8] = *(const uint4*)&Bt[(size_t)(bc + sr) * K + k0 + sseg * 8];
        __syncthreads();
        bf16x8 af[2], bfr[2];
#pragma unroll
        for (int i = 0; i < 2; ++i) {
            af[i]  = *(const bf16x8*)&As[wr * 32 + i * 16 + lrow][lq * 8];
            bfr[i] = *(const bf16x8*)&Bs[wc * 32 + i * 16 + lrow][lq * 8];
        }
#pragma unroll
        for (int i = 0; i < 2; ++i)
#pragma unroll
            for (int j = 0; j < 2; ++j)
                acc[i][j] = __builtin_amdgcn_mfma_f32_16x16x32_bf16(af[i], bfr[j], acc[i][j], 0, 0, 0);
        __syncthreads();
    }
#pragma unroll
    for (int i = 0; i < 2; ++i)
#pragma unroll
        for (int j = 0; j < 2; ++j) {
            int col = bc + wc * 32 + j * 16 + lrow;
            float bv = bias ? bias[col] : 0.f;
#pragma unroll
            for (int r = 0; r < 4; ++r) {
                int row = br + wr * 32 + i * 16 + lq * 4 + r;
                float v = acc[i][j][r] + bv;
                if (RELU) v = fmaxf(v, 0.f);
                stv(&C[(size_t)row * ldc + col], v);
            }
        }
}

// ---------- fp32 GEMM, LDS-tiled 64x64 ----------
template<bool RELU>
__global__ __launch_bounds__(256) void k_gemm_nn(int M, int N, int K,
        const float* __restrict__ A, int lda,
        const float* __restrict__ B, int ldb,
        float* __restrict__ C, int ldc,
        const float* __restrict__ bias) {
    __shared__ float As[16][65];
    __shared__ float Bs[16][65];
    int tid = threadIdx.x;
    int tx = tid & 15, ty = tid >> 4;
    int br = blockIdx.y * 64, bc = blockIdx.x * 64;
    float acc[4][4] = {};
    for (int k0 = 0; k0 < K; k0 += 16) {
#pragma unroll
        for (int c0 = 0; c0 < 4; ++c0) {
            int r = (tid >> 4) + c0 * 16, kk = tid & 15;
            int gr = br + r, gk = k0 + kk;
            As[kk][r] = (gr < M && gk < K) ? A[(size_t)gr * lda + gk] : 0.f;
        }
#pragma unroll
        for (int c0 = 0; c0 < 4; ++c0) {
            int col = tid & 63, kk = (tid >> 6) + c0 * 4;
            int gc = bc + col, gk = k0 + kk;
            Bs[kk][col] = (gc < N && gk < K) ? B[(size_t)gk * ldb + gc] : 0.f;
        }
        __syncthreads();
#pragma unroll
        for (int kk = 0; kk < 16; ++kk) {
            float av[4], bv[4];
#pragma unroll
            for (int i2 = 0; i2 < 4; ++i2) av[i2] = As[kk][ty + 16 * i2];
#pragma unroll
            for (int j2 = 0; j2 < 4; ++j2) bv[j2] = Bs[kk][tx + 16 * j2];
#pragma unroll
            for (int i2 = 0; i2 < 4; ++i2)
#pragma unroll
                for (int j2 = 0; j2 < 4; ++j2) acc[i2][j2] += av[i2] * bv[j2];
        }
        __syncthreads();
    }
#pragma unroll
    for (int i2 = 0; i2 < 4; ++i2)
#pragma unroll
        for (int j2 = 0; j2 < 4; ++j2) {
            int r = br + ty + 16 * i2, c = bc + tx + 16 * j2;
            if (r < M && c < N) {
                float v = acc[i2][j2];
                if (bias) v += bias[c];
                if (RELU) v = fmaxf(v, 0.f);
                C[(size_t)r * ldc + c] = v;
            }
        }
}

// ---------- SpMM wave-per-(row,chunk) ----------
template<int NC, int CH>
__global__ __launch_bounds__(256) void k_spmm_wave(
        const unsigned* __restrict__ BITS,
        const float* __restrict__ B, int ldb,
        float* __restrict__ C, int ldc) {
    int gw = blockIdx.x * 4 + (threadIdx.x >> 6);
    int lane = threadIdx.x & 63;
    int row = gw / CH, cb = (gw % CH) * NC;
    if (row >= 4096) return;
    float acc[NC];
#pragma unroll
    for (int j = 0; j < NC; ++j) acc[j] = 0.f;
    const unsigned* bw = &BITS[(size_t)row * 128];
#pragma unroll
    for (int i = 0; i < 2; ++i) {
        int wd = lane * 2 + i;
        unsigned bits = bw[wd];
        int base = wd * 32;
        while (bits) {
            int b = __ffs(bits) - 1; bits &= bits - 1;
            const float* br = &B[(size_t)(base + b) * ldb + cb];
#pragma unroll
            for (int j = 0; j < NC; ++j) acc[j] += br[j];
        }
    }
#pragma unroll
    for (int j = 0; j < NC; ++j) {
#pragma unroll
        for (int off = 1; off < 64; off <<= 1) acc[j] += __shfl_xor(acc[j], off, 64);
    }
    if (lane == 0)
#pragma unroll
        for (int j = 0; j < NC; ++j) C[(size_t)row * ldc + cb + j] = acc[j];
}

// ---------- MFMA flash: split-K z=3, DOUBLE-BUFFERED staging (1 barrier/tile),
// register prefetch overlaps global latency with MFMA+softmax ----------
__global__ __launch_bounds__(256) void k_flash(const ushort_t* __restrict__ Qg, int ldq,
                                               const ushort_t* __restrict__ Kg, int ldk,
                                               const ushort_t* __restrict__ VTg,
                                               ushort_t* __restrict__ OP0,
                                               ushort_t* __restrict__ OP12,
                                               float* __restrict__ Mp,
                                               float* __restrict__ Lp) {
    __shared__ ushort_t Ks[2][32][136];
    __shared__ ushort_t Vt[2][128][40];
    __shared__ ushort_t Ps[4][16][40];
    __shared__ float    as_[4][16];
    __shared__ float    ls_[4][16];
    const int tid = threadIdx.x;
    const int lane = tid & 63, wid = tid >> 6;
    const int lrow = lane & 15, lq = lane >> 4;
    const int qb = blockIdx.x * 64, hh = blockIdx.y, z = blockIdx.z;
    const int kt0 = z * 43, kt1 = (z == 2) ? 128 : kt0 + 43;
    const float scale = 0.08838834764831845f;   // 1/sqrt(128)
    // staging indices
    const int s0r = tid >> 4, sg = tid & 15;    // K rows [0,16) and +16
    const int d0 = tid >> 2, c8 = tid & 3;      // V cols [0,64) and +64
    bf16x8 qf[4];
    {
        const ushort_t* qrow = &Qg[(size_t)(qb + wid * 16 + lrow) * ldq + hh * 128 + lq * 8];
#pragma unroll
        for (int s = 0; s < 4; ++s) qf[s] = *(const bf16x8*)&qrow[s * 32];
    }
    f32x4 o[8];
#pragma unroll
    for (int ct = 0; ct < 8; ++ct) { o[ct][0] = 0.f; o[ct][1] = 0.f; o[ct][2] = 0.f; o[ct][3] = 0.f; }
    float m = -INFINITY, l = 0.f;
    // prologue: stage kt0 into buffer 0
    {
        *(uint4*)&Ks[0][s0r][sg * 8]      = *(const uint4*)&Kg[(size_t)(kt0 * 32 + s0r) * ldk + hh * 128 + sg * 8];
        *(uint4*)&Ks[0][s0r + 16][sg * 8] = *(const uint4*)&Kg[(size_t)(kt0 * 32 + s0r + 16) * ldk + hh * 128 + sg * 8];
        *(uint4*)&Vt[0][d0][c8 * 8]       = *(const uint4*)&VTg[(size_t)(hh * 128 + d0) * 4096 + kt0 * 32 + c8 * 8];
        *(uint4*)&Vt[0][d0 + 64][c8 * 8]  = *(const uint4*)&VTg[(size_t)(hh * 128 + d0 + 64) * 4096 + kt0 * 32 + c8 * 8];
    }
    __syncthreads();
    int buf = 0;
    for (int kt = kt0; kt < kt1; ++kt) {
        // prefetch next tile into VGPRs (overlaps with compute below)
        uint4 kr0, kr1, vr0, vr1;
        const bool pf = (kt + 1 < kt1);
        if (pf) {
            int kn = kt + 1;
            kr0 = *(const uint4*)&Kg[(size_t)(kn * 32 + s0r) * ldk + hh * 128 + sg * 8];
            kr1 = *(const uint4*)&Kg[(size_t)(kn * 32 + s0r + 16) * ldk + hh * 128 + sg * 8];
            vr0 = *(const uint4*)&VTg[(size_t)(hh * 128 + d0) * 4096 + kn * 32 + c8 * 8];
            vr1 = *(const uint4*)&VTg[(size_t)(hh * 128 + d0 + 64) * 4096 + kn * 32 + c8 * 8];
        }
        // QK on current buffer
        f32x4 sa[2];
#pragma unroll
        for (int c = 0; c < 2; ++c) { sa[c][0] = 0.f; sa[c][1] = 0.f; sa[c][2] = 0.f; sa[c][3] = 0.f; }
#pragma unroll
        for (int c = 0; c < 2; ++c)
#pragma unroll
            for (int st = 0; st < 4; ++st) {
                bf16x8 kf = *(const bf16x8*)&Ks[buf][c * 16 + lrow][st * 32 + lq * 8];
                sa[c] = __builtin_amdgcn_mfma_f32_16x16x32_bf16(kf, qf[st], sa[c], 0, 0, 0);
            }
        float s[8];
        float tm = -INFINITY;
#pragma unroll
        for (int c = 0; c < 2; ++c)
#pragma unroll
            for (int r = 0; r < 4; ++r) { float v = sa[c][r] * scale; s[c * 4 + r] = v; tm = fmaxf(tm, v); }
        tm = fmaxf(tm, __shfl_xor(tm, 16));
        tm = fmaxf(tm, __shfl_xor(tm, 32));
        bool up = tm > m;
        float mn = up ? tm : m;
        float a = up ? __expf(m - mn) : 1.0f;
        float su = 0.f;
        float p[8];
#pragma unroll
        for (int i = 0; i < 8; ++i) { p[i] = __expf(s[i] - mn); su += p[i]; }
        su += __shfl_xor(su, 16);
        su += __shfl_xor(su, 32);
        m = mn; l = l * a + su;
#pragma unroll
        for (int c = 0; c < 2; ++c) {
            uint2 w;
            w.x = pack2(p[c * 4 + 0], p[c * 4 + 1]);
            w.y = pack2(p[c * 4 + 2], p[c * 4 + 3]);
            *(uint2*)&Ps[wid][lrow][c * 16 + lq * 4] = w;
        }
        if (__any(up)) {
            if (lq == 0) as_[wid][lrow] = a;
            __builtin_amdgcn_s_waitcnt(0);
            float av[4];
#pragma unroll
            for (int r = 0; r < 4; ++r) av[r] = as_[wid][lq * 4 + r];
#pragma unroll
            for (int ct = 0; ct < 8; ++ct)
#pragma unroll
                for (int r = 0; r < 4; ++r) o[ct][r] *= av[r];
        } else {
            __builtin_amdgcn_s_waitcnt(0);
        }
        bf16x8 pfv = *(const bf16x8*)&Ps[wid][lrow][lq * 8];
#pragma unroll
        for (int ct = 0; ct < 8; ++ct) {
            bf16x8 vf = *(const bf16x8*)&Vt[buf][ct * 16 + lrow][lq * 8];
            o[ct] = __builtin_amdgcn_mfma_f32_16x16x32_bf16(pfv, vf, o[ct], 0, 0, 0);
        }
        // write prefetch into the other buffer, single barrier per tile
        if (pf) {
            *(uint4*)&Ks[buf ^ 1][s0r][sg * 8]      = kr0;
            *(uint4*)&Ks[buf ^ 1][s0r + 16][sg * 8] = kr1;
            *(uint4*)&Vt[buf ^ 1][d0][c8 * 8]       = vr0;
            *(uint4*)&Vt[buf ^ 1][d0 + 64][c8 * 8]  = vr1;
        }
        __syncthreads();
        buf ^= 1;
    }
    if (lq == 0) {
        Mp[(size_t)(z * 4 + hh) * 4096 + qb + wid * 16 + lrow] = m;
        Lp[(size_t)(z * 4 + hh) * 4096 + qb + wid * 16 + lrow] = l;
    }
    ushort_t* ob = (z == 0) ? OP0 : OP12 + (size_t)(z - 1) * 2097152;
#pragma unroll
    for (int ct = 0; ct < 8; ++ct)
#pragma unroll
        for (int r = 0; r < 4; ++r)
            ob[(size_t)(qb + wid * 16 + lq * 4 + r) * 512 + hh * 128 + ct * 16 + lrow] = f2bf(o[ct][r]);
}

// ---------- flash split-K combine (3 partials), in-place over OP0 ----------
__global__ __launch_bounds__(256) void k_fcomb(ushort_t* __restrict__ OP0,
                                               const ushort_t* __restrict__ OP12,
                                               const float* __restrict__ Mp,
                                               const float* __restrict__ Lp) {
    int idx = blockIdx.x * 256 + threadIdx.x;
    if (idx >= 4096 * 512) return;
    int row = idx >> 9, col = idx & 511;
    int hh = col >> 7;
    float m0 = Mp[hh * 4096 + row], m1 = Mp[(4 + hh) * 4096 + row], m2 = Mp[(8 + hh) * 4096 + row];
    float l0 = Lp[hh * 4096 + row], l1 = Lp[(4 + hh) * 4096 + row], l2 = Lp[(8 + hh) * 4096 + row];
    float mm = fmaxf(m0, fmaxf(m1, m2));
    float w0 = __expf(m0 - mm), w1 = __expf(m1 - mm), w2 = __expf(m2 - mm);
    float denom = l0 * w0 + l1 * w1 + l2 * w2;
    float o0 = bf2f(OP0[idx]), o1 = bf2f(OP12[idx]), o2 = bf2f(OP12[2097152 + idx]);
    OP0[idx] = f2bf((o0 * w0 + o1 * w1 + o2 * w2) / denom);
}

// ---------- residual add + layernorm ----------
__global__ __launch_bounds__(256) void k_add_ln(const float* __restrict__ A,
                                                const float* __restrict__ B,
                                                float* __restrict__ O,
                                                ushort_t* __restrict__ Ob,
                                                const float* __restrict__ g,
                                                const float* __restrict__ b) {
    __shared__ float xr[512];
    __shared__ float red[256];
    int row = blockIdx.x, t = threadIdx.x;
    const float* a = A + (size_t)row * 512;
    const float* bb = B + (size_t)row * 512;
    float ls = 0.f;
    for (int j = t; j < 512; j += 256) { float v = a[j] + bb[j]; xr[j] = v; ls += v; }
    red[t] = ls; __syncthreads();
    for (int o = 128; o; o >>= 1) { if (t < o) red[t] += red[t + o]; __syncthreads(); }
    float mean = red[0] / 512.0f; __syncthreads();
    float lv = 0.f;
    for (int j = t; j < 512; j += 256) { float d = xr[j] - mean; lv += d * d; }
    red[t] = lv; __syncthreads();
    for (int o = 128; o; o >>= 1) { if (t < o) red[t] += red[t + o]; __syncthreads(); }
    float inv = 1.0f / sqrtf(red[0] / 512.0f + 1e-5f);
    float* o_ = O + (size_t)row * 512;
    ushort_t* ob = Ob + (size_t)row * 512;
    for (int j = t; j < 512; j += 256) {
        float v = (xr[j] - mean) * inv * g[j] + b[j];
        o_[j] = v; ob[j] = f2bf(v);
    }
}

// ---------- fusion head ----------
__global__ __launch_bounds__(128) void k_fusion(const float* __restrict__ subv,
                                                const float* __restrict__ protv,
                                                const float* __restrict__ seqv,
                                                const float* __restrict__ Wtime,
                                                const float* __restrict__ btime,
                                                const float* __restrict__ Wout,
                                                const float* __restrict__ bout,
                                                const int* __restrict__ t_ptr,
                                                const int* __restrict__ lo_ptr,
                                                float* __restrict__ out) {
    __shared__ float cat[80];
    int t = threadIdx.x;
    int tval = guard_int(t_ptr[0], 0, 500);
    int L    = guard_int(lo_ptr[0], 0, 3);
    float tf = (float)((double)tval / 500.0);
    if (t < 20) {
        cat[t] = subv[t];
        cat[20 + t] = protv[t];
        cat[40 + t] = seqv[t];
        cat[60 + t] = tf * Wtime[t] + btime[t];
    }
    __syncthreads();
    for (int j = 0; j < L; ++j) {
        float acc = 0.f;
        if (t < 80) {
            for (int i2 = 0; i2 < 80; ++i2)
                acc += fmaxf(cat[i2], 0.f) * Wout[(size_t)j * 6400 + i2 * 80 + t];
            acc += bout[j * 80 + t];
        }
        __syncthreads();
        if (t < 80) cat[t] = acc;
        __syncthreads();
    }
    if (t < 80) out[t] = fmaxf(cat[t], 0.f);
    if (t < 20) out[80 + t] = seqv[t];
}

// ---------- launch ----------
extern "C" void kernel_launch(void* const* d_in, const int* in_sizes, int n_in,
                              void* d_out, int out_size, void* d_ws, size_t ws_size,
                              hipStream_t stream) {
    static const int EXP[39] = {
        81920, 65536, 200000, 2097152, 2560, 128, 8192, 64, 1280, 20,
        524288, 1024, 524288, 1024, 524288, 1024, 524288, 1024, 1024, 1024,
        2097152, 4096, 2097152, 1024, 1024, 1024, 10240, 20, 19200, 240,
        20, 20, 256, 4096, 4096, 131072, 1, 1, 1 };
    float code = 0.f;
    if (n_in != 39) code = 900.f;
    else {
        for (int i = 0; i < 39; ++i)
            if (in_sizes[i] != EXP[i]) { code = 500.f + 4.f * (float)i; break; }
    }
    const size_t REQ = (size_t)46 * 1024 * 1024;
    if (code == 0.f && ws_size < REQ) code = (float)(ws_size >> 20);
    float* out = (float*)d_out;
    if (code != 0.f) {
        k_sentinel<<<1, 128, 0, stream>>>(out, -code, out_size);
        return;
    }

    const float* x_in   = (const float*)d_in[0];
    const float* adjs_in= (const float*)d_in[1];
    const float* embfp  = (const float*)d_in[2];
    const float* embw   = (const float*)d_in[3];
    const float* gW1 = (const float*)d_in[4];  const float* gb1 = (const float*)d_in[5];
    const float* gW2 = (const float*)d_in[6];  const float* gb2 = (const float*)d_in[7];
    const float* gW3 = (const float*)d_in[8];  const float* gb3 = (const float*)d_in[9];
    const float* Wq  = (const float*)d_in[10]; const float* bq  = (const float*)d_in[11];
    const float* Wk  = (const float*)d_in[12]; const float* bk  = (const float*)d_in[13];
    const float* Wv  = (const float*)d_in[14]; const float* bv  = (const float*)d_in[15];
    const float* Wo  = (const float*)d_in[16]; const float* bo  = (const float*)d_in[17];
    const float* ln1g= (const float*)d_in[18]; const float* ln1b= (const float*)d_in[19];
    const float* Wff1= (const float*)d_in[20]; const float* bff1= (const float*)d_in[21];
    const float* Wff2= (const float*)d_in[22]; const float* bff2= (const float*)d_in[23];
    const float* ln2g= (const float*)d_in[24]; const float* ln2b= (const float*)d_in[25];
    const float* Wproj=(const float*)d_in[26]; const float* bproj=(const float*)d_in[27];
    const float* Woutw=(const float*)d_in[28]; const float* boutw=(const float*)d_in[29];
    const float* Wtime=(const float*)d_in[30]; const float* btime=(const float*)d_in[31];
    const int* fingerprints = (const int*)d_in[32];
    const int* words        = (const int*)d_in[33];
    const int* edge_index   = (const int*)d_in[35];
    const int* t_ptr        = (const int*)d_in[36];
    const int* lo_ptr       = (const int*)d_in[37];

    // ---- workspace (46 MiB) ----
    char* wsb = (char*)d_ws;
    float*    misc = (float*)wsb;
    float*    H    = (float*)(wsb + ((size_t)2  << 20));
    ushort_t* Hb   = (ushort_t*)(wsb + ((size_t)10 << 20));
    ushort_t* QKVb = (ushort_t*)(wsb + ((size_t)14 << 20));
    ushort_t* Ob   = (ushort_t*)(wsb + ((size_t)26 << 20));
    ushort_t* FFHb = (ushort_t*)(wsb + ((size_t)14 << 20));
    float*    T    = (float*)(wsb + ((size_t)30 << 20));
    ushort_t* OP12 = (ushort_t*)(wsb + ((size_t)30 << 20));
    ushort_t* Wscr = (ushort_t*)(wsb + ((size_t)38 << 20));
    ushort_t* VTg  = (ushort_t*)(wsb + ((size_t)42 << 20));
    unsigned* ADJB = (unsigned*)(wsb + ((size_t)26 << 20));
    float* pt0  = (float*)(wsb + ((size_t)14 << 20));
    float* ph1  = pt0 + 81920;
    float* pt1  = ph1 + 524288;
    float* ph2  = pt1 + 524288;
    float* Xoh  = misc;
    float* fpv  = misc + 81920;
    float* st0  = misc + 87040;
    float* sh1  = misc + 92160;
    float* st1  = misc + 124928;
    float* sh2  = misc + 157696;
    float* st2  = misc + 174080;
    float* sgo  = misc + 190464;
    float* subv = misc + 277504;
    float* protv= misc + 277536;
    float* seqv = misc + 277568;
    float* hmean= misc + 280000;
    float* wsum = misc + 281000;
    float* deg  = misc + 282000;
    float* bqkv = misc + 287000;
    float* Mp   = misc + 300000;
    float* Lp   = misc + 360000;

    auto g2 = [](int M, int N) { return dim3((unsigned)((N + 63) / 64), (unsigned)((M + 63) / 64), 1); };
    auto gm64  = [](int M, int N) { return dim3((unsigned)(N / 64), (unsigned)(M / 128), 1); };
    auto gm128 = [](int M, int N) { return dim3((unsigned)(N / 128), (unsigned)(M / 128), 1); };
    auto gs64  = [](int M, int N) { return dim3((unsigned)(N / 64), (unsigned)(M / 64), 1); };
    auto gt = [](int Kd, int Nd) { return dim3((unsigned)(Nd / 32), (unsigned)(Kd / 32), 1); };

    // 1. diffusion sampling
    k_sample<<<16, 256, 0, stream>>>(x_in, t_ptr, Xoh);

    // 2. substrate GCN (LDS-tiled fp32 GEMMs)
    k_gather_fp<<<20, 256, 0, stream>>>(embfp, fingerprints, fpv);
    k_gemm_nn<false><<<g2(256, 20), 256, 0, stream>>>(256, 20, 256, adjs_in, 256, fpv, 20, st0, 20, nullptr);
    k_gemm_nn<true ><<<g2(256, 128), 256, 0, stream>>>(256, 128, 20, st0, 20, gW1, 128, sh1, 128, gb1);
    k_gemm_nn<false><<<g2(256, 128), 256, 0, stream>>>(256, 128, 256, adjs_in, 256, sh1, 128, st1, 128, nullptr);
    k_gemm_nn<true ><<<g2(256, 64), 256, 0, stream>>>(256, 64, 128, st1, 128, gW2, 64, sh2, 64, gb2);
    k_gemm_nn<false><<<g2(256, 64), 256, 0, stream>>>(256, 64, 256, adjs_in, 256, sh2, 64, st2, 64, nullptr);
    k_gemm_nn<false><<<g2(256, 20), 256, 0, stream>>>(256, 20, 64, st2, 64, gW3, 20, sgo, 20, gb3);
    k_colmean<<<20, 256, 0, stream>>>(sgo, 256, 20, subv);

    // 3. transformer
    k_embed<<<8192, 256, 0, stream>>>(embw, words, H, Hb);
    for (int l = 0; l < 2; ++l) {
        k_castT4<<<dim3(16, 16, 4), 256, 0, stream>>>(Wq + (size_t)l * 262144, Wk + (size_t)l * 262144,
                                                      Wv + (size_t)l * 262144, Wo + (size_t)l * 262144, Wscr);
        k_gather3<<<6, 256, 0, stream>>>(bq + l * 512, bk + l * 512, bv + l * 512, bqkv);
        k_gemm_mfma2<64, false, true, ushort_t><<<gm64(4096, 1536), 256, 0, stream>>>(
            4096, 1536, 512, 512, Hb, Wscr, QKVb, 1536, bqkv, VTg);
        k_flash<<<dim3(64, 4, 3), 256, 0, stream>>>(QKVb, 1536, QKVb + 512, 1536, VTg, Ob, OP12, Mp, Lp);
        k_fcomb<<<8192, 256, 0, stream>>>(Ob, OP12, Mp, Lp);
        k_gemm_mfma64<false, float><<<gs64(4096, 512), 256, 0, stream>>>(
            4096, 512, 512, 512, Ob, Wscr + 786432, T, 512, bo + l * 512);
        k_add_ln<<<4096, 256, 0, stream>>>(H, T, H, Hb, ln1g + l * 512, ln1b + l * 512);
        k_castT<<<gt(512, 2048), 256, 0, stream>>>(Wff1 + (size_t)l * 1048576, Wscr, 512, 2048);
        k_gemm_mfma2<128, true, false, ushort_t><<<gm128(4096, 2048), 256, 0, stream>>>(
            4096, 2048, 512, 512, Hb, Wscr, FFHb, 2048, bff1 + l * 2048, nullptr);
        k_castT<<<gt(2048, 512), 256, 0, stream>>>(Wff2 + (size_t)l * 1048576, Wscr, 2048, 512);
        k_gemm_mfma64<false, float><<<gs64(4096, 512), 256, 0, stream>>>(
            4096, 512, 2048, 2048, FFHb, Wscr, T, 512, bff2 + l * 512);
        k_add_ln<<<4096, 256, 0, stream>>>(H, T, H, Hb, ln2g + l * 512, ln2b + l * 512);
    }

    // 4. seq = mean(H) @ Wproj + bproj
    k_colmean<<<512, 256, 0, stream>>>(H, 4096, 512, hmean);
    k_matvec20<<<20, 256, 0, stream>>>(512, 1.0f, hmean, Wproj, bproj, seqv);

    // 5. protein GCN
    hipMemsetAsync(ADJB, 0, (size_t)4096 * 128 * 4, stream);
    hipMemsetAsync(deg, 0, 4096 * 4, stream);
    k_scatter_bits<<<256, 256, 0, stream>>>(edge_index, ADJB);
    k_spmm_wave<20, 1><<<1024, 256, 0, stream>>>(ADJB, Xoh, 20, pt0, 20);
    k_gemm_nn<true ><<<g2(4096, 128), 256, 0, stream>>>(4096, 128, 20, pt0, 20, gW1, 128, ph1, 128, gb1);
    k_spmm_wave<32, 4><<<4096, 256, 0, stream>>>(ADJB, ph1, 128, pt1, 128);
    k_gemm_nn<true ><<<g2(4096, 64), 256, 0, stream>>>(4096, 64, 128, pt1, 128, gW2, 64, ph2, 64, gb2);
    k_degree<<<2048, 256, 0, stream>>>(ADJB, deg);
    k_wcolsum<<<64, 256, 0, stream>>>(ph2, 4096, 64, deg, wsum);
    k_matvec20<<<20, 256, 0, stream>>>(64, 1.0f / 4096.0f, wsum, gW3, gb3, protv);

    // 6. fusion head
    k_fusion<<<1, 128, 0, stream>>>(subv, protv, seqv, Wtime, btime, Woutw, boutw, t_ptr, lo_ptr, out);
}

// Round 19
// 837.156 us; speedup vs baseline: 1.4199x; 1.0223x over previous
//
#include <hip/hip_runtime.h>
#include <math.h>

typedef unsigned short ushort_t;
typedef __attribute__((ext_vector_type(8))) short bf16x8;
typedef __attribute__((ext_vector_type(4))) float f32x4;

// ---------- helpers ----------
__device__ inline float bf2f(unsigned u) { return __uint_as_float((u & 0xffffu) << 16); }
__device__ inline ushort_t f2bf(float f) {
    unsigned u = __float_as_uint(f);
    return (ushort_t)((u + 0x7fffu + ((u >> 16) & 1u)) >> 16);   // RNE
}
__device__ inline unsigned pack2(float a, float b) {
    return (unsigned)f2bf(a) | ((unsigned)f2bf(b) << 16);
}
__device__ inline void unpack8u(uint4 w, float* d) {
    d[0] = bf2f(w.x); d[1] = bf2f(w.x >> 16);
    d[2] = bf2f(w.y); d[3] = bf2f(w.y >> 16);
    d[4] = bf2f(w.z); d[5] = bf2f(w.z >> 16);
    d[6] = bf2f(w.w); d[7] = bf2f(w.w >> 16);
}
__device__ inline void stv(float* p, float v) { *p = v; }
__device__ inline void stv(ushort_t* p, float v) { *p = f2bf(v); }
__device__ inline int guard_int(int raw, int lo, int hi) {
    if (raw >= lo && raw <= hi) return raw;
    float f = __int_as_float(raw);
    int v = (int)f;
    return (v >= lo && v <= hi) ? v : lo;
}

// ---------- threefry2x32 (JAX partitionable, verified R7) ----------
__device__ inline void tf2x32(unsigned k0, unsigned k1, unsigned x0, unsigned x1,
                              unsigned& o0, unsigned& o1) {
    unsigned ks2 = k0 ^ k1 ^ 0x1BD11BDAu;
    x0 += k0; x1 += k1;
#define TFR(r) { x0 += x1; x1 = (x1 << (r)) | (x1 >> (32 - (r))); x1 ^= x0; }
    TFR(13) TFR(15) TFR(26) TFR(6)  x0 += k1;  x1 += ks2 + 1u;
    TFR(17) TFR(29) TFR(16) TFR(24) x0 += ks2; x1 += k0 + 2u;
    TFR(13) TFR(15) TFR(26) TFR(6)  x0 += k0;  x1 += k1 + 3u;
    TFR(17) TFR(29) TFR(16) TFR(24) x0 += k1;  x1 += ks2 + 4u;
    TFR(13) TFR(15) TFR(26) TFR(6)  x0 += ks2; x1 += k0 + 5u;
#undef TFR
    o0 = x0; o1 = x1;
}

__global__ void k_sentinel(float* __restrict__ out, float val, int n) {
    int i = blockIdx.x * 128 + threadIdx.x;
    if (i < n) out[i] = val;
}

// ---------- diffusion sampling -> one-hot X; also zeroes deg[4096] (used later in sec.5) ----------
__global__ __launch_bounds__(256) void k_sample(const float* __restrict__ x,
                                                const int* __restrict__ t_ptr,
                                                float* __restrict__ X,
                                                float* __restrict__ deg) {
    int i = blockIdx.x * 256 + threadIdx.x;
    if (i >= 4096) return;
    deg[i] = 0.f;                       // fold: deg memset (sec.5 consumer)
    int tval = guard_int(t_ptr[0], 0, 500);
    double tf = (double)tval / 500.0;
    const double sc = 0.008;
    const double PI_HALF = 1.5707963267948966;
    double num = cos((tf + sc) / (1.0 + sc) * PI_HALF);
    double den = cos(sc / (1.0 + sc) * PI_HALF);
    float ab = (float)((num * num) / (den * den));
    float phi = (1.0f - ab) / 20.0f;
    float xv[20]; float sx = 0.f;
    for (int j = 0; j < 20; ++j) { xv[j] = x[i * 20 + j]; sx += xv[j]; }
    float best = -1e30f; int bj = 0;
    for (int j = 0; j < 20; ++j) {
        float prob = fmaxf(ab * xv[j] + phi * sx, 0.0f);
        float lp = logf(prob + 1e-9f);
        unsigned m = (unsigned)(i * 20 + j);
        unsigned o0, o1;
        tf2x32(0u, 42u, 0u, m, o0, o1);
        unsigned bits = o0 ^ o1;
        float u = __uint_as_float((bits >> 9) | 0x3f800000u) - 1.0f;
        if (u < 1.1754943508222875e-38f) u = 1.1754943508222875e-38f;
        float gmb = -logf(-logf(u));
        float z = lp + gmb;
        if (z > best) { best = z; bj = j; }
    }
    for (int j = 0; j < 20; ++j) X[i * 20 + j] = (j == bj) ? 1.0f : 0.0f;
}

// ---------- small utility kernels ----------
__global__ __launch_bounds__(256) void k_gather_fp(const float* __restrict__ emb,
                                                   const int* __restrict__ idx,
                                                   float* __restrict__ out) {
    int i = blockIdx.x * 256 + threadIdx.x;
    if (i >= 256 * 20) return;
    int a = i / 20, d = i % 20;
    out[i] = emb[(size_t)idx[a] * 20 + d];
}

__global__ __launch_bounds__(256) void k_scatter_bits(const int* __restrict__ ei,
                                                      unsigned* __restrict__ bits) {
    int e = blockIdx.x * 256 + threadIdx.x;
    if (e >= 65536) return;
    int r = ei[e], c = ei[65536 + e];
    atomicOr(&bits[(size_t)r * 128 + (c >> 5)], 1u << (c & 31));
}

__global__ __launch_bounds__(256) void k_degree(const unsigned* __restrict__ BITS,
                                                float* __restrict__ deg) {
    int i = blockIdx.x * 256 + threadIdx.x;
    if (i >= 4096 * 128) return;
    unsigned bits = BITS[i];
    int base = (i & 127) * 32;
    while (bits) { int b = __ffs(bits) - 1; bits &= bits - 1; atomicAdd(&deg[base + b], 1.0f); }
}

__global__ __launch_bounds__(256) void k_embed(const float* __restrict__ embw,
                                               const int* __restrict__ words,
                                               float* __restrict__ H,
                                               ushort_t* __restrict__ Hb) {
    int idx = blockIdx.x * 256 + threadIdx.x;
    if (idx >= 4096 * 512) return;
    int pos = idx >> 9, d = idx & 511;
    float e = embw[(size_t)words[pos] * 512 + d];
    float expo = (float)(d >> 1) * (1.0f / 256.0f);
    float ang = (float)pos * exp2f(-expo * 13.287712379549449f);
    float pe = (d & 1) ? cosf(ang) : sinf(ang);
    float v = e + pe;
    H[idx] = v; Hb[idx] = f2bf(v);
}

// colmean; when adjz != nullptr (512-block call, post-transformer) also zeroes the
// 2 MiB protein bitmap (aliased region is free by then; scatter runs after)
__global__ __launch_bounds__(256) void k_colmean(const float* __restrict__ M, int R, int C,
                                                 float* __restrict__ out,
                                                 uint4* __restrict__ adjz) {
    __shared__ float red[256];
    int c = blockIdx.x, t = threadIdx.x;
    if (adjz) adjz[blockIdx.x * 256 + t] = make_uint4(0, 0, 0, 0);
    float s = 0.f;
    for (int r = t; r < R; r += 256) s += M[(size_t)r * C + c];
    red[t] = s; __syncthreads();
    for (int o = 128; o; o >>= 1) { if (t < o) red[t] += red[t + o]; __syncthreads(); }
    if (t == 0) out[c] = red[0] / (float)R;
}

__global__ __launch_bounds__(256) void k_wcolsum(const float* __restrict__ M, int R, int C,
                                                 const float* __restrict__ w,
                                                 float* __restrict__ out) {
    __shared__ float red[256];
    int c = blockIdx.x, t = threadIdx.x;
    float s = 0.f;
    for (int r = t; r < R; r += 256) s += w[r] * M[(size_t)r * C + c];
    red[t] = s; __syncthreads();
    for (int o = 128; o; o >>= 1) { if (t < o) red[t] += red[t + o]; __syncthreads(); }
    if (t == 0) out[c] = red[0];
}

__global__ __launch_bounds__(256) void k_matvec20(int D, float scale,
                                                  const float* __restrict__ vec,
                                                  const float* __restrict__ W,
                                                  const float* __restrict__ bias,
                                                  float* __restrict__ out) {
    __shared__ float red[256];
    int c = blockIdx.x, t = threadIdx.x;
    float s = 0.f;
    for (int d = t; d < D; d += 256) s += vec[d] * W[(size_t)d * 20 + c];
    red[t] = s; __syncthreads();
    for (int o = 128; o; o >>= 1) { if (t < o) red[t] += red[t + o]; __syncthreads(); }
    if (t == 0) out[c] = red[0] * scale + bias[c];
}

// ---------- weight cast+transpose: fp32 [K,N] -> bf16 [N,K] ----------
__global__ __launch_bounds__(256) void k_castT(const float* __restrict__ in,
                                               ushort_t* __restrict__ out,
                                               int Kd, int Nd) {
    __shared__ float t[32][33];
    int bx = blockIdx.x * 32, by = blockIdx.y * 32;
    int tx = threadIdx.x & 31, ty = threadIdx.x >> 5;
#pragma unroll
    for (int i = 0; i < 4; ++i)
        t[ty + i * 8][tx] = in[(size_t)(by + ty + i * 8) * Nd + bx + tx];
    __syncthreads();
#pragma unroll
    for (int i = 0; i < 4; ++i)
        out[(size_t)(bx + ty + i * 8) * Kd + by + tx] = f2bf(t[tx][ty + i * 8]);
}

// batched: z<4 -> 4x [512,512] fp32 -> bf16 transposed; z==4 -> QKV bias gather
__global__ __launch_bounds__(256) void k_castT5(const float* __restrict__ in0,
                                                const float* __restrict__ in1,
                                                const float* __restrict__ in2,
                                                const float* __restrict__ in3,
                                                ushort_t* __restrict__ out,
                                                const float* __restrict__ ba,
                                                const float* __restrict__ bb,
                                                const float* __restrict__ bc,
                                                float* __restrict__ bout) {
    int z = blockIdx.z;
    if (z == 4) {                        // bias gather plane (6 blocks do work)
        int i = (blockIdx.y * 16 + blockIdx.x) * 256 + threadIdx.x;
        if (i < 1536) bout[i] = (i < 512) ? ba[i] : (i < 1024) ? bb[i - 512] : bc[i - 1024];
        return;
    }
    __shared__ float t[32][33];
    const float* in = (z == 0) ? in0 : (z == 1) ? in1 : (z == 2) ? in2 : in3;
    ushort_t* o = out + (size_t)z * 262144;
    int bx = blockIdx.x * 32, by = blockIdx.y * 32;
    int tx = threadIdx.x & 31, ty = threadIdx.x >> 5;
#pragma unroll
    for (int i = 0; i < 4; ++i)
        t[ty + i * 8][tx] = in[(size_t)(by + ty + i * 8) * 512 + bx + tx];
    __syncthreads();
#pragma unroll
    for (int i = 0; i < 4; ++i)
        o[(size_t)(bx + ty + i * 8) * 512 + by + tx] = f2bf(t[tx][ty + i * 8]);
}

// ---------- MFMA bf16 GEMM: BM=128 x BN tile; VTR: cols>=1024 write transposed VTg ----------
template<int BN, bool RELU, bool VTR, typename TC>
__global__ __launch_bounds__(256) void k_gemm_mfma2(int M, int N, int K, int lda,
        const ushort_t* __restrict__ A,
        const ushort_t* __restrict__ Bt,
        TC* __restrict__ C, int ldc,
        const float* __restrict__ bias,
        ushort_t* __restrict__ VT) {
    constexpr int NJ = BN / 32;
    __shared__ ushort_t As[128][40];
    __shared__ ushort_t Bs[BN][40];
    int tid = threadIdx.x;
    int lane = tid & 63, wave = tid >> 6;
    int wr = wave >> 1, wc = wave & 1;
    int lrow = lane & 15, lq = lane >> 4;
    int br = blockIdx.y * 128, bc = blockIdx.x * BN;
    f32x4 acc[4][NJ];
#pragma unroll
    for (int i = 0; i < 4; ++i)
#pragma unroll
        for (int j = 0; j < NJ; ++j) { acc[i][j][0] = 0.f; acc[i][j][1] = 0.f; acc[i][j][2] = 0.f; acc[i][j][3] = 0.f; }
    int sr = tid >> 2, sseg = tid & 3;
    for (int k0 = 0; k0 < K; k0 += 32) {
#pragma unroll
        for (int it = 0; it < 2; ++it)
            *(uint4*)&As[sr + it * 64][sseg * 8] = *(const uint4*)&A[(size_t)(br + sr + it * 64) * lda + k0 + sseg * 8];
#pragma unroll
        for (int it = 0; it < BN / 64; ++it)
            *(uint4*)&Bs[sr + it * 64][sseg * 8] = *(const uint4*)&Bt[(size_t)(bc + sr + it * 64) * K + k0 + sseg * 8];
        __syncthreads();
        bf16x8 af[4], bfr[NJ];
#pragma unroll
        for (int i = 0; i < 4; ++i) af[i] = *(const bf16x8*)&As[wr * 64 + i * 16 + lrow][lq * 8];
#pragma unroll
        for (int j = 0; j < NJ; ++j) bfr[j] = *(const bf16x8*)&Bs[wc * (BN / 2) + j * 16 + lrow][lq * 8];
#pragma unroll
        for (int i = 0; i < 4; ++i)
#pragma unroll
            for (int j = 0; j < NJ; ++j)
                acc[i][j] = __builtin_amdgcn_mfma_f32_16x16x32_bf16(af[i], bfr[j], acc[i][j], 0, 0, 0);
        __syncthreads();
    }
#pragma unroll
    for (int i = 0; i < 4; ++i)
#pragma unroll
        for (int j = 0; j < NJ; ++j) {
            int col = bc + wc * (BN / 2) + j * 16 + lrow;
            float bv = bias ? bias[col] : 0.f;
            int row0 = br + wr * 64 + i * 16 + lq * 4;
            if (VTR && col >= 1024) {
                uint2 w;
                w.x = pack2(acc[i][j][0] + bv, acc[i][j][1] + bv);
                w.y = pack2(acc[i][j][2] + bv, acc[i][j][3] + bv);
                *(uint2*)&VT[(size_t)(col - 1024) * 4096 + row0] = w;
            } else {
#pragma unroll
                for (int r = 0; r < 4; ++r) {
                    float v = acc[i][j][r] + bv;
                    if (RELU) v = fmaxf(v, 0.f);
                    stv(&C[(size_t)(row0 + r) * ldc + col], v);
                }
            }
        }
}

// ---------- MFMA bf16 GEMM 64x64 tile (R9-proven) — N=512 shapes: grid 512 = 2/CU ----------
template<bool RELU, typename TC>
__global__ __launch_bounds__(256) void k_gemm_mfma64(int M, int N, int K, int lda,
        const ushort_t* __restrict__ A,
        const ushort_t* __restrict__ Bt,
        TC* __restrict__ C, int ldc,
        const float* __restrict__ bias) {
    __shared__ ushort_t As[64][40];
    __shared__ ushort_t Bs[64][40];
    int tid = threadIdx.x;
    int lane = tid & 63, wave = tid >> 6;
    int wr = wave >> 1, wc = wave & 1;
    int lrow = lane & 15, lq = lane >> 4;
    int br = blockIdx.y * 64, bc = blockIdx.x * 64;
    f32x4 acc[2][2];
#pragma unroll
    for (int i = 0; i < 2; ++i)
#pragma unroll
        for (int j = 0; j < 2; ++j) { acc[i][j][0] = 0.f; acc[i][j][1] = 0.f; acc[i][j][2] = 0.f; acc[i][j][3] = 0.f; }
    int sr = tid >> 2, sseg = tid & 3;
    for (int k0 = 0; k0 < K; k0 += 32) {
        *(uint4*)&As[sr][sseg * 8] = *(const uint4*)&A[(size_t)(br + sr) * lda + k0 + sseg * 8];
        *(uint4*)&Bs[sr][sseg * 8] = *(const uint4*)&Bt[(size_t)(bc + sr) * K + k0 + sseg * 8];
        __syncthreads();
        bf16x8 af[2], bfr[2];
#pragma unroll
        for (int i = 0; i < 2; ++i) {
            af[i]  = *(const bf16x8*)&As[wr * 32 + i * 16 + lrow][lq * 8];
            bfr[i] = *(const bf16x8*)&Bs[wc * 32 + i * 16 + lrow][lq * 8];
        }
#pragma unroll
        for (int i = 0; i < 2; ++i)
#pragma unroll
            for (int j = 0; j < 2; ++j)
                acc[i][j] = __builtin_amdgcn_mfma_f32_16x16x32_bf16(af[i], bfr[j], acc[i][j], 0, 0, 0);
        __syncthreads();
    }
#pragma unroll
    for (int i = 0; i < 2; ++i)
#pragma unroll
        for (int j = 0; j < 2; ++j) {
            int col = bc + wc * 32 + j * 16 + lrow;
            float bv = bias ? bias[col] : 0.f;
#pragma unroll
            for (int r = 0; r < 4; ++r) {
                int row = br + wr * 32 + i * 16 + lq * 4 + r;
                float v = acc[i][j][r] + bv;
                if (RELU) v = fmaxf(v, 0.f);
                stv(&C[(size_t)row * ldc + col], v);
            }
        }
}

// ---------- fp32 GEMM, LDS-tiled 64x64 ----------
template<bool RELU>
__global__ __launch_bounds__(256) void k_gemm_nn(int M, int N, int K,
        const float* __restrict__ A, int lda,
        const float* __restrict__ B, int ldb,
        float* __restrict__ C, int ldc,
        const float* __restrict__ bias) {
    __shared__ float As[16][65];
    __shared__ float Bs[16][65];
    int tid = threadIdx.x;
    int tx = tid & 15, ty = tid >> 4;
    int br = blockIdx.y * 64, bc = blockIdx.x * 64;
    float acc[4][4] = {};
    for (int k0 = 0; k0 < K; k0 += 16) {
#pragma unroll
        for (int c0 = 0; c0 < 4; ++c0) {
            int r = (tid >> 4) + c0 * 16, kk = tid & 15;
            int gr = br + r, gk = k0 + kk;
            As[kk][r] = (gr < M && gk < K) ? A[(size_t)gr * lda + gk] : 0.f;
        }
#pragma unroll
        for (int c0 = 0; c0 < 4; ++c0) {
            int col = tid & 63, kk = (tid >> 6) + c0 * 4;
            int gc = bc + col, gk = k0 + kk;
            Bs[kk][col] = (gc < N && gk < K) ? B[(size_t)gk * ldb + gc] : 0.f;
        }
        __syncthreads();
#pragma unroll
        for (int kk = 0; kk < 16; ++kk) {
            float av[4], bv[4];
#pragma unroll
            for (int i2 = 0; i2 < 4; ++i2) av[i2] = As[kk][ty + 16 * i2];
#pragma unroll
            for (int j2 = 0; j2 < 4; ++j2) bv[j2] = Bs[kk][tx + 16 * j2];
#pragma unroll
            for (int i2 = 0; i2 < 4; ++i2)
#pragma unroll
                for (int j2 = 0; j2 < 4; ++j2) acc[i2][j2] += av[i2] * bv[j2];
        }
        __syncthreads();
    }
#pragma unroll
    for (int i2 = 0; i2 < 4; ++i2)
#pragma unroll
        for (int j2 = 0; j2 < 4; ++j2) {
            int r = br + ty + 16 * i2, c = bc + tx + 16 * j2;
            if (r < M && c < N) {
                float v = acc[i2][j2];
                if (bias) v += bias[c];
                if (RELU) v = fmaxf(v, 0.f);
                C[(size_t)r * ldc + c] = v;
            }
        }
}

// ---------- SpMM wave-per-(row,chunk) ----------
template<int NC, int CH>
__global__ __launch_bounds__(256) void k_spmm_wave(
        const unsigned* __restrict__ BITS,
        const float* __restrict__ B, int ldb,
        float* __restrict__ C, int ldc) {
    int gw = blockIdx.x * 4 + (threadIdx.x >> 6);
    int lane = threadIdx.x & 63;
    int row = gw / CH, cb = (gw % CH) * NC;
    if (row >= 4096) return;
    float acc[NC];
#pragma unroll
    for (int j = 0; j < NC; ++j) acc[j] = 0.f;
    const unsigned* bw = &BITS[(size_t)row * 128];
#pragma unroll
    for (int i = 0; i < 2; ++i) {
        int wd = lane * 2 + i;
        unsigned bits = bw[wd];
        int base = wd * 32;
        while (bits) {
            int b = __ffs(bits) - 1; bits &= bits - 1;
            const float* br = &B[(size_t)(base + b) * ldb + cb];
#pragma unroll
            for (int j = 0; j < NC; ++j) acc[j] += br[j];
        }
    }
#pragma unroll
    for (int j = 0; j < NC; ++j) {
#pragma unroll
        for (int off = 1; off < 64; off <<= 1) acc[j] += __shfl_xor(acc[j], off, 64);
    }
    if (lane == 0)
#pragma unroll
        for (int j = 0; j < NC; ++j) C[(size_t)row * ldc + cb + j] = acc[j];
}

// ---------- MFMA flash: split-K z=3, double-buffered, rescale-skip ----------
__global__ __launch_bounds__(256) void k_flash(const ushort_t* __restrict__ Qg, int ldq,
                                               const ushort_t* __restrict__ Kg, int ldk,
                                               const ushort_t* __restrict__ VTg,
                                               ushort_t* __restrict__ OP0,
                                               ushort_t* __restrict__ OP12,
                                               float* __restrict__ Mp,
                                               float* __restrict__ Lp) {
    __shared__ ushort_t Ks[2][32][136];
    __shared__ ushort_t Vt[2][128][40];
    __shared__ ushort_t Ps[4][16][40];
    __shared__ float    as_[4][16];
    const int tid = threadIdx.x;
    const int lane = tid & 63, wid = tid >> 6;
    const int lrow = lane & 15, lq = lane >> 4;
    const int qb = blockIdx.x * 64, hh = blockIdx.y, z = blockIdx.z;
    const int kt0 = z * 43, kt1 = (z == 2) ? 128 : kt0 + 43;
    const float scale = 0.08838834764831845f;   // 1/sqrt(128)
    const int s0r = tid >> 4, sg = tid & 15;
    const int d0 = tid >> 2, c8 = tid & 3;
    bf16x8 qf[4];
    {
        const ushort_t* qrow = &Qg[(size_t)(qb + wid * 16 + lrow) * ldq + hh * 128 + lq * 8];
#pragma unroll
        for (int s = 0; s < 4; ++s) qf[s] = *(const bf16x8*)&qrow[s * 32];
    }
    f32x4 o[8];
#pragma unroll
    for (int ct = 0; ct < 8; ++ct) { o[ct][0] = 0.f; o[ct][1] = 0.f; o[ct][2] = 0.f; o[ct][3] = 0.f; }
    float m = -INFINITY, l = 0.f;
    {
        *(uint4*)&Ks[0][s0r][sg * 8]      = *(const uint4*)&Kg[(size_t)(kt0 * 32 + s0r) * ldk + hh * 128 + sg * 8];
        *(uint4*)&Ks[0][s0r + 16][sg * 8] = *(const uint4*)&Kg[(size_t)(kt0 * 32 + s0r + 16) * ldk + hh * 128 + sg * 8];
        *(uint4*)&Vt[0][d0][c8 * 8]       = *(const uint4*)&VTg[(size_t)(hh * 128 + d0) * 4096 + kt0 * 32 + c8 * 8];
        *(uint4*)&Vt[0][d0 + 64][c8 * 8]  = *(const uint4*)&VTg[(size_t)(hh * 128 + d0 + 64) * 4096 + kt0 * 32 + c8 * 8];
    }
    __syncthreads();
    int buf = 0;
    for (int kt = kt0; kt < kt1; ++kt) {
        uint4 kr0, kr1, vr0, vr1;
        const bool pf = (kt + 1 < kt1);
        if (pf) {
            int kn = kt + 1;
            kr0 = *(const uint4*)&Kg[(size_t)(kn * 32 + s0r) * ldk + hh * 128 + sg * 8];
            kr1 = *(const uint4*)&Kg[(size_t)(kn * 32 + s0r + 16) * ldk + hh * 128 + sg * 8];
            vr0 = *(const uint4*)&VTg[(size_t)(hh * 128 + d0) * 4096 + kn * 32 + c8 * 8];
            vr1 = *(const uint4*)&VTg[(size_t)(hh * 128 + d0 + 64) * 4096 + kn * 32 + c8 * 8];
        }
        f32x4 sa[2];
#pragma unroll
        for (int c = 0; c < 2; ++c) { sa[c][0] = 0.f; sa[c][1] = 0.f; sa[c][2] = 0.f; sa[c][3] = 0.f; }
#pragma unroll
        for (int c = 0; c < 2; ++c)
#pragma unroll
            for (int st = 0; st < 4; ++st) {
                bf16x8 kf = *(const bf16x8*)&Ks[buf][c * 16 + lrow][st * 32 + lq * 8];
                sa[c] = __builtin_amdgcn_mfma_f32_16x16x32_bf16(kf, qf[st], sa[c], 0, 0, 0);
            }
        float s[8];
        float tm = -INFINITY;
#pragma unroll
        for (int c = 0; c < 2; ++c)
#pragma unroll
            for (int r = 0; r < 4; ++r) { float v = sa[c][r] * scale; s[c * 4 + r] = v; tm = fmaxf(tm, v); }
        tm = fmaxf(tm, __shfl_xor(tm, 16));
        tm = fmaxf(tm, __shfl_xor(tm, 32));
        bool up = tm > m;
        float mn = up ? tm : m;
        float a = up ? __expf(m - mn) : 1.0f;
        float su = 0.f;
        float p[8];
#pragma unroll
        for (int i = 0; i < 8; ++i) { p[i] = __expf(s[i] - mn); su += p[i]; }
        su += __shfl_xor(su, 16);
        su += __shfl_xor(su, 32);
        m = mn; l = l * a + su;
#pragma unroll
        for (int c = 0; c < 2; ++c) {
            uint2 w;
            w.x = pack2(p[c * 4 + 0], p[c * 4 + 1]);
            w.y = pack2(p[c * 4 + 2], p[c * 4 + 3]);
            *(uint2*)&Ps[wid][lrow][c * 16 + lq * 4] = w;
        }
        if (__any(up)) {
            if (lq == 0) as_[wid][lrow] = a;
            __builtin_amdgcn_s_waitcnt(0);
            float av[4];
#pragma unroll
            for (int r = 0; r < 4; ++r) av[r] = as_[wid][lq * 4 + r];
#pragma unroll
            for (int ct = 0; ct < 8; ++ct)
#pragma unroll
                for (int r = 0; r < 4; ++r) o[ct][r] *= av[r];
        } else {
            __builtin_amdgcn_s_waitcnt(0);
        }
        bf16x8 pfv = *(const bf16x8*)&Ps[wid][lrow][lq * 8];
#pragma unroll
        for (int ct = 0; ct < 8; ++ct) {
            bf16x8 vf = *(const bf16x8*)&Vt[buf][ct * 16 + lrow][lq * 8];
            o[ct] = __builtin_amdgcn_mfma_f32_16x16x32_bf16(pfv, vf, o[ct], 0, 0, 0);
        }
        if (pf) {
            *(uint4*)&Ks[buf ^ 1][s0r][sg * 8]      = kr0;
            *(uint4*)&Ks[buf ^ 1][s0r + 16][sg * 8] = kr1;
            *(uint4*)&Vt[buf ^ 1][d0][c8 * 8]       = vr0;
            *(uint4*)&Vt[buf ^ 1][d0 + 64][c8 * 8]  = vr1;
        }
        __syncthreads();
        buf ^= 1;
    }
    if (lq == 0) {
        Mp[(size_t)(z * 4 + hh) * 4096 + qb + wid * 16 + lrow] = m;
        Lp[(size_t)(z * 4 + hh) * 4096 + qb + wid * 16 + lrow] = l;
    }
    ushort_t* ob = (z == 0) ? OP0 : OP12 + (size_t)(z - 1) * 2097152;
#pragma unroll
    for (int ct = 0; ct < 8; ++ct)
#pragma unroll
        for (int r = 0; r < 4; ++r)
            ob[(size_t)(qb + wid * 16 + lq * 4 + r) * 512 + hh * 128 + ct * 16 + lrow] = f2bf(o[ct][r]);
}

// ---------- flash split-K combine, x8 vectorized (uint4 = 8 bf16/thread) ----------
__global__ __launch_bounds__(256) void k_fcomb(ushort_t* __restrict__ OP0,
                                               const ushort_t* __restrict__ OP12,
                                               const float* __restrict__ Mp,
                                               const float* __restrict__ Lp) {
    int i8 = blockIdx.x * 256 + threadIdx.x;      // 262144 groups of 8 bf16
    if (i8 >= 262144) return;
    int e = i8 * 8;
    int row = e >> 9, col = e & 511;
    int hh = col >> 7;                             // 8 consecutive cols share a head
    float m0 = Mp[hh * 4096 + row], m1 = Mp[(4 + hh) * 4096 + row], m2 = Mp[(8 + hh) * 4096 + row];
    float l0 = Lp[hh * 4096 + row], l1 = Lp[(4 + hh) * 4096 + row], l2 = Lp[(8 + hh) * 4096 + row];
    float mm = fmaxf(m0, fmaxf(m1, m2));
    float w0 = __expf(m0 - mm), w1 = __expf(m1 - mm), w2 = __expf(m2 - mm);
    float inv = 1.0f / (l0 * w0 + l1 * w1 + l2 * w2);
    w0 *= inv; w1 *= inv; w2 *= inv;
    float a[8], b[8], c[8];
    unpack8u(*(const uint4*)&OP0[e], a);
    unpack8u(*(const uint4*)&OP12[e], b);
    unpack8u(*(const uint4*)&OP12[2097152 + e], c);
    uint4 w;
    w.x = pack2(a[0] * w0 + b[0] * w1 + c[0] * w2, a[1] * w0 + b[1] * w1 + c[1] * w2);
    w.y = pack2(a[2] * w0 + b[2] * w1 + c[2] * w2, a[3] * w0 + b[3] * w1 + c[3] * w2);
    w.z = pack2(a[4] * w0 + b[4] * w1 + c[4] * w2, a[5] * w0 + b[5] * w1 + c[5] * w2);
    w.w = pack2(a[6] * w0 + b[6] * w1 + c[6] * w2, a[7] * w0 + b[7] * w1 + c[7] * w2);
    *(uint4*)&OP0[e] = w;
}

// ---------- residual add + layernorm ----------
__global__ __launch_bounds__(256) void k_add_ln(const float* __restrict__ A,
                                                const float* __restrict__ B,
                                                float* __restrict__ O,
                                                ushort_t* __restrict__ Ob,
                                                const float* __restrict__ g,
                                                const float* __restrict__ b) {
    __shared__ float xr[512];
    __shared__ float red[256];
    int row = blockIdx.x, t = threadIdx.x;
    const float* a = A + (size_t)row * 512;
    const float* bb = B + (size_t)row * 512;
    float ls = 0.f;
    for (int j = t; j < 512; j += 256) { float v = a[j] + bb[j]; xr[j] = v; ls += v; }
    red[t] = ls; __syncthreads();
    for (int o = 128; o; o >>= 1) { if (t < o) red[t] += red[t + o]; __syncthreads(); }
    float mean = red[0] / 512.0f; __syncthreads();
    float lv = 0.f;
    for (int j = t; j < 512; j += 256) { float d = xr[j] - mean; lv += d * d; }
    red[t] = lv; __syncthreads();
    for (int o = 128; o; o >>= 1) { if (t < o) red[t] += red[t + o]; __syncthreads(); }
    float inv = 1.0f / sqrtf(red[0] / 512.0f + 1e-5f);
    float* o_ = O + (size_t)row * 512;
    ushort_t* ob = Ob + (size_t)row * 512;
    for (int j = t; j < 512; j += 256) {
        float v = (xr[j] - mean) * inv * g[j] + b[j];
        o_[j] = v; ob[j] = f2bf(v);
    }
}

// ---------- fusion head ----------
__global__ __launch_bounds__(128) void k_fusion(const float* __restrict__ subv,
                                                const float* __restrict__ protv,
                                                const float* __restrict__ seqv,
                                                const float* __restrict__ Wtime,
                                                const float* __restrict__ btime,
                                                const float* __restrict__ Wout,
                                                const float* __restrict__ bout,
                                                const int* __restrict__ t_ptr,
                                                const int* __restrict__ lo_ptr,
                                                float* __restrict__ out) {
    __shared__ float cat[80];
    int t = threadIdx.x;
    int tval = guard_int(t_ptr[0], 0, 500);
    int L    = guard_int(lo_ptr[0], 0, 3);
    float tf = (float)((double)tval / 500.0);
    if (t < 20) {
        cat[t] = subv[t];
        cat[20 + t] = protv[t];
        cat[40 + t] = seqv[t];
        cat[60 + t] = tf * Wtime[t] + btime[t];
    }
    __syncthreads();
    for (int j = 0; j < L; ++j) {
        float acc = 0.f;
        if (t < 80) {
            for (int i2 = 0; i2 < 80; ++i2)
                acc += fmaxf(cat[i2], 0.f) * Wout[(size_t)j * 6400 + i2 * 80 + t];
            acc += bout[j * 80 + t];
        }
        __syncthreads();
        if (t < 80) cat[t] = acc;
        __syncthreads();
    }
    if (t < 80) out[t] = fmaxf(cat[t], 0.f);
    if (t < 20) out[80 + t] = seqv[t];
}

// ---------- launch ----------
extern "C" void kernel_launch(void* const* d_in, const int* in_sizes, int n_in,
                              void* d_out, int out_size, void* d_ws, size_t ws_size,
                              hipStream_t stream) {
    static const int EXP[39] = {
        81920, 65536, 200000, 2097152, 2560, 128, 8192, 64, 1280, 20,
        524288, 1024, 524288, 1024, 524288, 1024, 524288, 1024, 1024, 1024,
        2097152, 4096, 2097152, 1024, 1024, 1024, 10240, 20, 19200, 240,
        20, 20, 256, 4096, 4096, 131072, 1, 1, 1 };
    float code = 0.f;
    if (n_in != 39) code = 900.f;
    else {
        for (int i = 0; i < 39; ++i)
            if (in_sizes[i] != EXP[i]) { code = 500.f + 4.f * (float)i; break; }
    }
    const size_t REQ = (size_t)46 * 1024 * 1024;
    if (code == 0.f && ws_size < REQ) code = (float)(ws_size >> 20);
    float* out = (float*)d_out;
    if (code != 0.f) {
        k_sentinel<<<1, 128, 0, stream>>>(out, -code, out_size);
        return;
    }

    const float* x_in   = (const float*)d_in[0];
    const float* adjs_in= (const float*)d_in[1];
    const float* embfp  = (const float*)d_in[2];
    const float* embw   = (const float*)d_in[3];
    const float* gW1 = (const float*)d_in[4];  const float* gb1 = (const float*)d_in[5];
    const float* gW2 = (const float*)d_in[6];  const float* gb2 = (const float*)d_in[7];
    const float* gW3 = (const float*)d_in[8];  const float* gb3 = (const float*)d_in[9];
    const float* Wq  = (const float*)d_in[10]; const float* bq  = (const float*)d_in[11];
    const float* Wk  = (const float*)d_in[12]; const float* bk  = (const float*)d_in[13];
    const float* Wv  = (const float*)d_in[14]; const float* bv  = (const float*)d_in[15];
    const float* Wo  = (const float*)d_in[16]; const float* bo  = (const float*)d_in[17];
    const float* ln1g= (const float*)d_in[18]; const float* ln1b= (const float*)d_in[19];
    const float* Wff1= (const float*)d_in[20]; const float* bff1= (const float*)d_in[21];
    const float* Wff2= (const float*)d_in[22]; const float* bff2= (const float*)d_in[23];
    const float* ln2g= (const float*)d_in[24]; const float* ln2b= (const float*)d_in[25];
    const float* Wproj=(const float*)d_in[26]; const float* bproj=(const float*)d_in[27];
    const float* Woutw=(const float*)d_in[28]; const float* boutw=(const float*)d_in[29];
    const float* Wtime=(const float*)d_in[30]; const float* btime=(const float*)d_in[31];
    const int* fingerprints = (const int*)d_in[32];
    const int* words        = (const int*)d_in[33];
    const int* edge_index   = (const int*)d_in[35];
    const int* t_ptr        = (const int*)d_in[36];
    const int* lo_ptr       = (const int*)d_in[37];

    // ---- workspace (46 MiB) ----
    char* wsb = (char*)d_ws;
    float*    misc = (float*)wsb;
    float*    H    = (float*)(wsb + ((size_t)2  << 20));
    ushort_t* Hb   = (ushort_t*)(wsb + ((size_t)10 << 20));
    ushort_t* QKVb = (ushort_t*)(wsb + ((size_t)14 << 20));
    ushort_t* Ob   = (ushort_t*)(wsb + ((size_t)26 << 20));
    ushort_t* FFHb = (ushort_t*)(wsb + ((size_t)14 << 20));
    float*    T    = (float*)(wsb + ((size_t)30 << 20));
    ushort_t* OP12 = (ushort_t*)(wsb + ((size_t)30 << 20));
    ushort_t* Wscr = (ushort_t*)(wsb + ((size_t)38 << 20));
    ushort_t* VTg  = (ushort_t*)(wsb + ((size_t)42 << 20));
    unsigned* ADJB = (unsigned*)(wsb + ((size_t)26 << 20));
    float* pt0  = (float*)(wsb + ((size_t)14 << 20));
    float* ph1  = pt0 + 81920;
    float* pt1  = ph1 + 524288;
    float* ph2  = pt1 + 524288;
    float* Xoh  = misc;
    float* fpv  = misc + 81920;
    float* st0  = misc + 87040;
    float* sh1  = misc + 92160;
    float* st1  = misc + 124928;
    float* sh2  = misc + 157696;
    float* st2  = misc + 174080;
    float* sgo  = misc + 190464;
    float* subv = misc + 277504;
    float* protv= misc + 277536;
    float* seqv = misc + 277568;
    float* hmean= misc + 280000;
    float* wsum = misc + 281000;
    float* deg  = misc + 282000;
    float* bqkv = misc + 287000;
    float* Mp   = misc + 300000;
    float* Lp   = misc + 360000;

    auto g2 = [](int M, int N) { return dim3((unsigned)((N + 63) / 64), (unsigned)((M + 63) / 64), 1); };
    auto gm64  = [](int M, int N) { return dim3((unsigned)(N / 64), (unsigned)(M / 128), 1); };
    auto gm128 = [](int M, int N) { return dim3((unsigned)(N / 128), (unsigned)(M / 128), 1); };
    auto gs64  = [](int M, int N) { return dim3((unsigned)(N / 64), (unsigned)(M / 64), 1); };
    auto gt = [](int Kd, int Nd) { return dim3((unsigned)(Nd / 32), (unsigned)(Kd / 32), 1); };

    // 1. diffusion sampling (also zeroes deg)
    k_sample<<<16, 256, 0, stream>>>(x_in, t_ptr, Xoh, deg);

    // 2. substrate GCN (LDS-tiled fp32 GEMMs)
    k_gather_fp<<<20, 256, 0, stream>>>(embfp, fingerprints, fpv);
    k_gemm_nn<false><<<g2(256, 20), 256, 0, stream>>>(256, 20, 256, adjs_in, 256, fpv, 20, st0, 20, nullptr);
    k_gemm_nn<true ><<<g2(256, 128), 256, 0, stream>>>(256, 128, 20, st0, 20, gW1, 128, sh1, 128, gb1);
    k_gemm_nn<false><<<g2(256, 128), 256, 0, stream>>>(256, 128, 256, adjs_in, 256, sh1, 128, st1, 128, nullptr);
    k_gemm_nn<true ><<<g2(256, 64), 256, 0, stream>>>(256, 64, 128, st1, 128, gW2, 64, sh2, 64, gb2);
    k_gemm_nn<false><<<g2(256, 64), 256, 0, stream>>>(256, 64, 256, adjs_in, 256, sh2, 64, st2, 64, nullptr);
    k_gemm_nn<false><<<g2(256, 20), 256, 0, stream>>>(256, 20, 64, st2, 64, gW3, 20, sgo, 20, gb3);
    k_colmean<<<20, 256, 0, stream>>>(sgo, 256, 20, subv, nullptr);

    // 3. transformer
    k_embed<<<8192, 256, 0, stream>>>(embw, words, H, Hb);
    for (int l = 0; l < 2; ++l) {
        k_castT5<<<dim3(16, 16, 5), 256, 0, stream>>>(Wq + (size_t)l * 262144, Wk + (size_t)l * 262144,
                                                      Wv + (size_t)l * 262144, Wo + (size_t)l * 262144, Wscr,
                                                      bq + l * 512, bk + l * 512, bv + l * 512, bqkv);
        k_gemm_mfma2<64, false, true, ushort_t><<<gm64(4096, 1536), 256, 0, stream>>>(
            4096, 1536, 512, 512, Hb, Wscr, QKVb, 1536, bqkv, VTg);
        k_flash<<<dim3(64, 4, 3), 256, 0, stream>>>(QKVb, 1536, QKVb + 512, 1536, VTg, Ob, OP12, Mp, Lp);
        k_fcomb<<<1024, 256, 0, stream>>>(Ob, OP12, Mp, Lp);
        k_gemm_mfma64<false, float><<<gs64(4096, 512), 256, 0, stream>>>(
            4096, 512, 512, 512, Ob, Wscr + 786432, T, 512, bo + l * 512);
        k_add_ln<<<4096, 256, 0, stream>>>(H, T, H, Hb, ln1g + l * 512, ln1b + l * 512);
        k_castT<<<gt(512, 2048), 256, 0, stream>>>(Wff1 + (size_t)l * 1048576, Wscr, 512, 2048);
        k_gemm_mfma2<128, true, false, ushort_t><<<gm128(4096, 2048), 256, 0, stream>>>(
            4096, 2048, 512, 512, Hb, Wscr, FFHb, 2048, bff1 + l * 2048, nullptr);
        k_castT<<<gt(2048, 512), 256, 0, stream>>>(Wff2 + (size_t)l * 1048576, Wscr, 2048, 512);
        k_gemm_mfma64<false, float><<<gs64(4096, 512), 256, 0, stream>>>(
            4096, 512, 2048, 2048, FFHb, Wscr, T, 512, bff2 + l * 512);
        k_add_ln<<<4096, 256, 0, stream>>>(H, T, H, Hb, ln2g + l * 512, ln2b + l * 512);
    }

    // 4. seq = mean(H) @ Wproj + bproj  (colmean also zeroes ADJB: region free, scatter follows)
    k_colmean<<<512, 256, 0, stream>>>(H, 4096, 512, hmean, (uint4*)ADJB);
    k_matvec20<<<20, 256, 0, stream>>>(512, 1.0f, hmean, Wproj, bproj, seqv);

    // 5. protein GCN
    k_scatter_bits<<<256, 256, 0, stream>>>(edge_index, ADJB);
    k_spmm_wave<20, 1><<<1024, 256, 0, stream>>>(ADJB, Xoh, 20, pt0, 20);
    k_gemm_nn<true ><<<g2(4096, 128), 256, 0, stream>>>(4096, 128, 20, pt0, 20, gW1, 128, ph1, 128, gb1);
    k_spmm_wave<32, 4><<<4096, 256, 0, stream>>>(ADJB, ph1, 128, pt1, 128);
    k_gemm_nn<true ><<<g2(4096, 64), 256, 0, stream>>>(4096, 64, 128, pt1, 128, gW2, 64, ph2, 64, gb2);
    k_degree<<<2048, 256, 0, stream>>>(ADJB, deg);
    k_wcolsum<<<64, 256, 0, stream>>>(ph2, 4096, 64, deg, wsum);
    k_matvec20<<<20, 256, 0, stream>>>(64, 1.0f / 4096.0f, wsum, gW3, gb3, protv);

    // 6. fusion head
    k_fusion<<<1, 128, 0, stream>>>(subv, protv, seqv, Wtime, btime, Woutw, boutw, t_ptr, lo_ptr, out);
}